// Round 1
// baseline (889.616 us; speedup 1.0000x reference)
//
#include <hip/hip_runtime.h>
#include <hip/hip_bf16.h>

// ---------------------------------------------------------------------------
// MQ Parallel-FF Transformer block, MI355X (gfx950)
// Round 0: correctness-first bf16-MFMA implementation.
//   B=4, N=1024, DIM=1024, HEADS=16, DIM_HEAD=64, INNER=1024, FF_INNER=4096
// ---------------------------------------------------------------------------

typedef __attribute__((ext_vector_type(8))) short bf16x8;   // 8 bf16 (4 VGPR)
typedef __attribute__((ext_vector_type(4))) short s16x4;
typedef __attribute__((ext_vector_type(4))) float f32x4;

__device__ __forceinline__ short f2b(float f) {
  union { float f; unsigned u; } v; v.f = f;
  unsigned r = (v.u + 0x7fffu + ((v.u >> 16) & 1u)) >> 16;
  return (short)r;
}

// --------------------------- f32 -> bf16 convert ---------------------------
__global__ __launch_bounds__(256) void cvt_kernel(const float* __restrict__ in,
                                                  short* __restrict__ out, int n4) {
  int i = blockIdx.x * 256 + threadIdx.x;
  if (i >= n4) return;
  float4 v = ((const float4*)in)[i];
  s16x4 o = { f2b(v.x), f2b(v.y), f2b(v.z), f2b(v.w) };
  ((s16x4*)out)[i] = o;
}

// --------------------------------- LayerNorm -------------------------------
// One block per row of 1024 f32. Writes bf16 and/or f32 normalized output.
__global__ __launch_bounds__(256) void ln_kernel(const float* __restrict__ in,
                                                 const float* __restrict__ gamma,
                                                 short* __restrict__ out16,
                                                 float* __restrict__ out32) {
  int row = blockIdx.x;
  int t = threadIdx.x;
  float4 v = ((const float4*)(in + (size_t)row * 1024))[t];
  float s  = v.x + v.y + v.z + v.w;
  float sq = v.x*v.x + v.y*v.y + v.z*v.z + v.w*v.w;
  __shared__ float ssum[256], ssq[256];
  ssum[t] = s; ssq[t] = sq;
  __syncthreads();
  for (int o = 128; o > 0; o >>= 1) {
    if (t < o) { ssum[t] += ssum[t + o]; ssq[t] += ssq[t + o]; }
    __syncthreads();
  }
  float mu  = ssum[0] * (1.0f / 1024.0f);
  float var = ssq[0] * (1.0f / 1024.0f) - mu * mu;
  float rs  = rsqrtf(var + 1e-5f);
  float4 g = ((const float4*)gamma)[t];
  float o0 = (v.x - mu) * rs * g.x;
  float o1 = (v.y - mu) * rs * g.y;
  float o2 = (v.z - mu) * rs * g.z;
  float o3 = (v.w - mu) * rs * g.w;
  if (out16) {
    s16x4 o = { f2b(o0), f2b(o1), f2b(o2), f2b(o3) };
    ((s16x4*)out16)[(size_t)row * 256 + t] = o;
  }
  if (out32) {
    float4 o = { o0, o1, o2, o3 };
    ((float4*)out32)[(size_t)row * 256 + t] = o;
  }
}

// ----------------------------------- GEMM ----------------------------------
// C[M,N] = A[M,K] @ B[K,N]  (A,B bf16 row-major; ldb = B row stride)
// 128x128 tile, BK=32, 256 threads (4 waves, 2x2), 16x16x32 bf16 MFMA.
// EPI 0: out16 = bf16(acc*scale)
// EPI 1: out32 = acc + res            (f32)
// EPI 2 (DUAL): out16 = bf16(silu(acc2)*acc)  where acc2 uses B cols +4096
template<int EPI, bool DUAL>
__global__ __launch_bounds__(256) void gemm_kernel(
    const short* __restrict__ A, const short* __restrict__ B,
    int M, int N, int K, int ldb,
    short* __restrict__ out16, float* __restrict__ out32,
    const float* __restrict__ res, float scale)
{
  __shared__ short As[128 * 32];
  __shared__ short Bs[(DUAL ? 2 : 1) * 128 * 32];   // stored N-major: [n][k]

  int t = threadIdx.x;
  int lane = t & 63, wave = t >> 6;
  int wm = wave >> 1, wn = wave & 1;
  int lrow = lane & 15, lgrp = lane >> 4;
  int m0 = blockIdx.y * 128, n0 = blockIdx.x * 128;

  f32x4 acc[4][4];
  f32x4 acc2[4][4];
  const f32x4 zero = { 0.f, 0.f, 0.f, 0.f };
#pragma unroll
  for (int i = 0; i < 4; i++)
#pragma unroll
    for (int j = 0; j < 4; j++) { acc[i][j] = zero; if (DUAL) acc2[i][j] = zero; }

  int ar = t >> 2, ac = (t & 3) * 8;      // A: 4 threads/row, 2 row passes
  int bk = t >> 4, bc = (t & 15) * 8;     // B: 16 threads/row, 2 row passes

  for (int k0 = 0; k0 < K; k0 += 32) {
    __syncthreads();
#pragma unroll
    for (int p = 0; p < 2; p++) {
      int row = ar + p * 64;
      *(int4*)&As[row * 32 + ac] =
          *(const int4*)&A[(size_t)(m0 + row) * K + k0 + ac];
    }
#pragma unroll
    for (int p = 0; p < 2; p++) {
      int krow = bk + p * 16;
      int4 d = *(const int4*)&B[(size_t)(k0 + krow) * ldb + n0 + bc];
      const short* ds = (const short*)&d;
#pragma unroll
      for (int i = 0; i < 8; i++) Bs[(bc + i) * 32 + krow] = ds[i];
      if (DUAL) {
        int4 d2 = *(const int4*)&B[(size_t)(k0 + krow) * ldb + 4096 + n0 + bc];
        const short* ds2 = (const short*)&d2;
#pragma unroll
        for (int i = 0; i < 8; i++) Bs[128 * 32 + (bc + i) * 32 + krow] = ds2[i];
      }
    }
    __syncthreads();

    bf16x8 af[4], bfr[4], bfr2[4];
#pragma unroll
    for (int mf = 0; mf < 4; mf++)
      af[mf] = *(const bf16x8*)&As[(wm * 64 + mf * 16 + lrow) * 32 + lgrp * 8];
#pragma unroll
    for (int nf = 0; nf < 4; nf++)
      bfr[nf] = *(const bf16x8*)&Bs[(wn * 64 + nf * 16 + lrow) * 32 + lgrp * 8];
    if (DUAL) {
#pragma unroll
      for (int nf = 0; nf < 4; nf++)
        bfr2[nf] = *(const bf16x8*)&Bs[128 * 32 + (wn * 64 + nf * 16 + lrow) * 32 + lgrp * 8];
    }
#pragma unroll
    for (int mf = 0; mf < 4; mf++)
#pragma unroll
      for (int nf = 0; nf < 4; nf++) {
        acc[mf][nf] = __builtin_amdgcn_mfma_f32_16x16x32_bf16(af[mf], bfr[nf], acc[mf][nf], 0, 0, 0);
        if (DUAL)
          acc2[mf][nf] = __builtin_amdgcn_mfma_f32_16x16x32_bf16(af[mf], bfr2[nf], acc2[mf][nf], 0, 0, 0);
      }
  }

#pragma unroll
  for (int mf = 0; mf < 4; mf++)
#pragma unroll
    for (int nf = 0; nf < 4; nf++)
#pragma unroll
      for (int r = 0; r < 4; r++) {
        int row = m0 + wm * 64 + mf * 16 + lgrp * 4 + r;
        int col = n0 + wn * 64 + nf * 16 + lrow;
        float v = acc[mf][nf][r];
        if (EPI == 0) {
          out16[(size_t)row * N + col] = f2b(v * scale);
        } else if (EPI == 1) {
          out32[(size_t)row * N + col] = v + res[(size_t)row * N + col];
        } else {
          float gate = acc2[mf][nf][r];
          float sig = 1.0f / (1.0f + __expf(-gate));
          out16[(size_t)row * N + col] = f2b(v * gate * sig);
        }
      }
}

// ------------------------------- Attention ---------------------------------
// MQA flash attention. Grid (16 q-tiles, B*H=64). 1 wave/block.
// q: [B,N,H*64] bf16 (pre-scaled), kv: [B,N,128] bf16 (k|v), ao: [B,N,H*64] bf16
__global__ __launch_bounds__(64) void attn_kernel(const short* __restrict__ q,
                                                  const short* __restrict__ kv,
                                                  short* __restrict__ ao)
{
  __shared__ short Ks[64 * 64];   // [kv][d]
  __shared__ short Vs[64 * 64];   // transposed: [d][kv]
  __shared__ short Ps[64 * 64];   // [q][kv]

  int lane = threadIdx.x;
  int lrow = lane & 15, lgrp = lane >> 4;
  int qt = blockIdx.x, bh = blockIdx.y;
  int b = bh >> 4, h = bh & 15;

  bf16x8 qf[4][2];
  const short* qb = q + ((size_t)(b * 1024 + qt * 64)) * 1024 + h * 64;
#pragma unroll
  for (int mf = 0; mf < 4; mf++)
#pragma unroll
    for (int kk = 0; kk < 2; kk++)
      qf[mf][kk] = *(const bf16x8*)&qb[(size_t)(mf * 16 + lrow) * 1024 + kk * 32 + lgrp * 8];

  f32x4 oacc[4][4];
  float m_[4][4], l_[4][4];
  const f32x4 zero = { 0.f, 0.f, 0.f, 0.f };
#pragma unroll
  for (int i = 0; i < 4; i++)
#pragma unroll
    for (int j = 0; j < 4; j++) {
      oacc[i][j] = zero; m_[i][j] = -3.0e38f; l_[i][j] = 0.f;
    }

  for (int j0 = 0; j0 < 1024; j0 += 64) {
    __syncthreads();
    // load K tile [64][64] row-major, V tile transposed [d][kv]
    {
      const short* kvb = kv + ((size_t)(b * 1024 + j0 + lane)) * 128;
#pragma unroll
      for (int c = 0; c < 64; c += 8) {
        *(int4*)&Ks[lane * 64 + c] = *(const int4*)&kvb[c];
        int4 vv = *(const int4*)&kvb[64 + c];
        const short* vs = (const short*)&vv;
#pragma unroll
        for (int i = 0; i < 8; i++) Vs[(c + i) * 64 + lane] = vs[i];
      }
    }
    __syncthreads();

    // S = Q @ K^T   (64x64)
    f32x4 sacc[4][4];
#pragma unroll
    for (int i = 0; i < 4; i++)
#pragma unroll
      for (int j = 0; j < 4; j++) sacc[i][j] = zero;

    bf16x8 kf[4][2];
#pragma unroll
    for (int nf = 0; nf < 4; nf++)
#pragma unroll
      for (int kk = 0; kk < 2; kk++)
        kf[nf][kk] = *(const bf16x8*)&Ks[(nf * 16 + lrow) * 64 + kk * 32 + lgrp * 8];
#pragma unroll
    for (int mf = 0; mf < 4; mf++)
#pragma unroll
      for (int nf = 0; nf < 4; nf++)
#pragma unroll
        for (int kk = 0; kk < 2; kk++)
          sacc[mf][nf] = __builtin_amdgcn_mfma_f32_16x16x32_bf16(qf[mf][kk], kf[nf][kk], sacc[mf][nf], 0, 0, 0);

    // online softmax; rows of a fragment live on 16 lanes sharing lgrp
#pragma unroll
    for (int mf = 0; mf < 4; mf++)
#pragma unroll
      for (int r = 0; r < 4; r++) {
        float mx = fmaxf(fmaxf(sacc[mf][0][r], sacc[mf][1][r]),
                         fmaxf(sacc[mf][2][r], sacc[mf][3][r]));
#pragma unroll
        for (int o = 8; o >= 1; o >>= 1) mx = fmaxf(mx, __shfl_xor(mx, o));
        float mnew = fmaxf(m_[mf][r], mx);
        float corr = __expf(m_[mf][r] - mnew);
        float rs = 0.f;
#pragma unroll
        for (int nf = 0; nf < 4; nf++) {
          float p = __expf(sacc[mf][nf][r] - mnew);
          sacc[mf][nf][r] = p;
          rs += p;
        }
#pragma unroll
        for (int o = 8; o >= 1; o >>= 1) rs += __shfl_xor(rs, o);
        l_[mf][r] = l_[mf][r] * corr + rs;
        m_[mf][r] = mnew;
#pragma unroll
        for (int nf = 0; nf < 4; nf++) {
          oacc[mf][nf][r] *= corr;
          Ps[(mf * 16 + lgrp * 4 + r) * 64 + nf * 16 + lrow] = f2b(sacc[mf][nf][r]);
        }
      }
    __syncthreads();

    // O += P @ V
    bf16x8 vf[4][2];
#pragma unroll
    for (int nf = 0; nf < 4; nf++)
#pragma unroll
      for (int kk = 0; kk < 2; kk++)
        vf[nf][kk] = *(const bf16x8*)&Vs[(nf * 16 + lrow) * 64 + kk * 32 + lgrp * 8];
#pragma unroll
    for (int mf = 0; mf < 4; mf++) {
      bf16x8 pf[2];
#pragma unroll
      for (int kk = 0; kk < 2; kk++)
        pf[kk] = *(const bf16x8*)&Ps[(mf * 16 + lrow) * 64 + kk * 32 + lgrp * 8];
#pragma unroll
      for (int nf = 0; nf < 4; nf++)
#pragma unroll
        for (int kk = 0; kk < 2; kk++)
          oacc[mf][nf] = __builtin_amdgcn_mfma_f32_16x16x32_bf16(pf[kk], vf[nf][kk], oacc[mf][nf], 0, 0, 0);
    }
  }

  // write O / l  ->  ao[b, n, h*64+d]
#pragma unroll
  for (int mf = 0; mf < 4; mf++)
#pragma unroll
    for (int nf = 0; nf < 4; nf++)
#pragma unroll
      for (int r = 0; r < 4; r++) {
        int qrow = qt * 64 + mf * 16 + lgrp * 4 + r;
        float val = oacc[mf][nf][r] / l_[mf][r];
        ao[((size_t)(b * 1024 + qrow)) * 1024 + h * 64 + nf * 16 + lrow] = f2b(val);
      }
}

// ------------------------------- launcher ----------------------------------
extern "C" void kernel_launch(void* const* d_in, const int* in_sizes, int n_in,
                              void* d_out, int out_size, void* d_ws, size_t ws_size,
                              hipStream_t stream) {
  const float* x     = (const float*)d_in[0];
  const float* y     = (const float*)d_in[1];
  const float* g1    = (const float*)d_in[2];
  const float* g2    = (const float*)d_in[3];
  const float* g_out = (const float*)d_in[4];
  const float* Wq    = (const float*)d_in[5];
  const float* Wkv   = (const float*)d_in[6];
  const float* Wo    = (const float*)d_in[7];
  const float* Wff1  = (const float*)d_in[8];
  const float* Wff2  = (const float*)d_in[9];

  char* ws = (char*)d_ws;
  size_t off = 0;
  auto alloc = [&](size_t bytes) { char* p = ws + off; off += bytes; return p; };
  short* wq16   = (short*)alloc((size_t)1024 * 1024 * 2);
  short* wkv16  = (short*)alloc((size_t)1024 * 128 * 2);
  short* wo16   = (short*)alloc((size_t)1024 * 1024 * 2);
  short* wff1b  = (short*)alloc((size_t)1024 * 8192 * 2);
  short* wff2b  = (short*)alloc((size_t)4096 * 1024 * 2);
  short* xn16   = (short*)alloc((size_t)4096 * 1024 * 2);
  short* yn16   = (short*)alloc((size_t)4096 * 1024 * 2);
  float* ynf    = (float*)alloc((size_t)4096 * 1024 * 4);
  short* q16    = (short*)alloc((size_t)4096 * 1024 * 2);
  short* kv16   = (short*)alloc((size_t)4096 * 128 * 2);
  short* ao16   = (short*)alloc((size_t)4096 * 1024 * 2);
  float* lnout  = (float*)alloc((size_t)4096 * 1024 * 4);
  short* act16  = (short*)alloc((size_t)4096 * 4096 * 2);
  float* outf   = (float*)d_out;

  // weight conversion f32 -> bf16
  cvt_kernel<<<(1024 * 1024 / 4) / 256, 256, 0, stream>>>(Wq, wq16, 1024 * 1024 / 4);
  cvt_kernel<<<(1024 * 128 / 4) / 256, 256, 0, stream>>>(Wkv, wkv16, 1024 * 128 / 4);
  cvt_kernel<<<(1024 * 1024 / 4) / 256, 256, 0, stream>>>(Wo, wo16, 1024 * 1024 / 4);
  cvt_kernel<<<(1024 * 8192 / 4) / 256, 256, 0, stream>>>(Wff1, wff1b, 1024 * 8192 / 4);
  cvt_kernel<<<(4096 * 1024 / 4) / 256, 256, 0, stream>>>(Wff2, wff2b, 4096 * 1024 / 4);

  // LayerNorms
  ln_kernel<<<4096, 256, 0, stream>>>(x, g1, xn16, nullptr);
  ln_kernel<<<4096, 256, 0, stream>>>(y, g2, yn16, ynf);

  // q = (xn @ Wq) * 1/8    kv = yn @ Wkv
  gemm_kernel<0, false><<<dim3(8, 32), 256, 0, stream>>>(
      xn16, wq16, 4096, 1024, 1024, 1024, q16, nullptr, nullptr, 0.125f);
  gemm_kernel<0, false><<<dim3(1, 32), 256, 0, stream>>>(
      yn16, wkv16, 4096, 128, 1024, 128, kv16, nullptr, nullptr, 1.0f);

  // attention
  attn_kernel<<<dim3(16, 64), 64, 0, stream>>>(q16, kv16, ao16);

  // out = attn @ Wo + yn   (f32, into d_out as scratch)
  gemm_kernel<1, false><<<dim3(8, 32), 256, 0, stream>>>(
      ao16, wo16, 4096, 1024, 1024, 1024, nullptr, outf, ynf, 1.0f);

  // ln_out = LN(out) * g_out  (f32)
  ln_kernel<<<4096, 256, 0, stream>>>(outf, g_out, nullptr, lnout);

  // act = silu(gate) * val   (fused dual-B GEMM over Wff1)
  gemm_kernel<2, true><<<dim3(32, 32), 256, 0, stream>>>(
      yn16, wff1b, 4096, 4096, 1024, 8192, act16, nullptr, nullptr, 1.0f);

  // d_out = act @ Wff2 + ln_out
  gemm_kernel<1, false><<<dim3(8, 32), 256, 0, stream>>>(
      act16, wff2b, 4096, 1024, 4096, 1024, nullptr, outf, lnout, 1.0f);
}

// Round 2
// 524.988 us; speedup vs baseline: 1.6945x; 1.6945x over previous
//
#include <hip/hip_runtime.h>
#include <hip/hip_bf16.h>

// ---------------------------------------------------------------------------
// MQ Parallel-FF Transformer block, MI355X (gfx950)
// Round 1: m97-structure GEMM — weights pre-transposed to [N][K] bf16,
//          global_load_lds(16B) staging, direct ds_read_b128 fragments.
//   B=4, N=1024, DIM=1024, HEADS=16, DIM_HEAD=64, INNER=1024, FF_INNER=4096
// ---------------------------------------------------------------------------

typedef __attribute__((ext_vector_type(8))) short bf16x8;   // 8 bf16 (4 VGPR)
typedef __attribute__((ext_vector_type(4))) short s16x4;
typedef __attribute__((ext_vector_type(4))) float f32x4;

__device__ __forceinline__ short f2b(float f) {
  union { float f; unsigned u; } v; v.f = f;
  unsigned r = (v.u + 0x7fffu + ((v.u >> 16) & 1u)) >> 16;
  return (short)r;
}

__device__ __forceinline__ void gload16(const short* g, short* l) {
  __builtin_amdgcn_global_load_lds(
      (const __attribute__((address_space(1))) void*)g,
      (__attribute__((address_space(3))) void*)l, 16, 0, 0);
}

// ---------------- f32 [K][N] -> bf16 [N][K] transpose-convert ---------------
// 32x32 tile per 256-thread block. grid = (N/32, K/32)
__global__ __launch_bounds__(256) void cvtT_kernel(const float* __restrict__ in,
                                                   short* __restrict__ out,
                                                   int K, int N) {
  __shared__ float tile[32][33];
  int n0 = blockIdx.x * 32, k0 = blockIdx.y * 32;
  int tx = threadIdx.x & 7, ty = threadIdx.x >> 3;     // 8 x 32
  float4 v = *(const float4*)&in[(size_t)(k0 + ty) * N + n0 + tx * 4];
  tile[ty][tx * 4 + 0] = v.x;
  tile[ty][tx * 4 + 1] = v.y;
  tile[ty][tx * 4 + 2] = v.z;
  tile[ty][tx * 4 + 3] = v.w;
  __syncthreads();
  s16x4 o = { f2b(tile[tx * 4 + 0][ty]), f2b(tile[tx * 4 + 1][ty]),
              f2b(tile[tx * 4 + 2][ty]), f2b(tile[tx * 4 + 3][ty]) };
  *(s16x4*)&out[(size_t)(n0 + ty) * K + k0 + tx * 4] = o;
}

// --------------------------------- LayerNorm -------------------------------
__global__ __launch_bounds__(256) void ln_kernel(const float* __restrict__ in,
                                                 const float* __restrict__ gamma,
                                                 short* __restrict__ out16,
                                                 float* __restrict__ out32) {
  int row = blockIdx.x;
  int t = threadIdx.x;
  float4 v = ((const float4*)(in + (size_t)row * 1024))[t];
  float s  = v.x + v.y + v.z + v.w;
  float sq = v.x*v.x + v.y*v.y + v.z*v.z + v.w*v.w;
  __shared__ float ssum[256], ssq[256];
  ssum[t] = s; ssq[t] = sq;
  __syncthreads();
  for (int o = 128; o > 0; o >>= 1) {
    if (t < o) { ssum[t] += ssum[t + o]; ssq[t] += ssq[t + o]; }
    __syncthreads();
  }
  float mu  = ssum[0] * (1.0f / 1024.0f);
  float var = ssq[0] * (1.0f / 1024.0f) - mu * mu;
  float rs  = rsqrtf(var + 1e-5f);
  float4 g = ((const float4*)gamma)[t];
  float o0 = (v.x - mu) * rs * g.x;
  float o1 = (v.y - mu) * rs * g.y;
  float o2 = (v.z - mu) * rs * g.z;
  float o3 = (v.w - mu) * rs * g.w;
  if (out16) {
    s16x4 o = { f2b(o0), f2b(o1), f2b(o2), f2b(o3) };
    ((s16x4*)out16)[(size_t)row * 256 + t] = o;
  }
  if (out32) {
    float4 o = { o0, o1, o2, o3 };
    ((float4*)out32)[(size_t)row * 256 + t] = o;
  }
}

// ----------------------------------- GEMM ----------------------------------
// C[M,N] = A[M,K] @ B^T   where B is stored [N][K] bf16 (K-contiguous).
// 128x128 tile, BK=32, 256 threads (4 waves, 2x2), 16x16x32 bf16 MFMA,
// global_load_lds 16B staging into linear LDS tiles.
// EPI 0: out16 = bf16(acc*scale)
// EPI 1: out32 = acc + res                       (f32)
// EPI 2 (DUAL): out16 = bf16(silu(acc2)*acc)     acc2 uses B rows +4096
template<int EPI, bool DUAL>
__global__ __launch_bounds__(256) void gemm_kernel(
    const short* __restrict__ A, const short* __restrict__ B,
    int M, int N, int K,
    short* __restrict__ out16, float* __restrict__ out32,
    const float* __restrict__ res, float scale)
{
  __shared__ __align__(16) short As[128 * 32];
  __shared__ __align__(16) short Bs[128 * 32];
  __shared__ __align__(16) short Bs2[DUAL ? 128 * 32 : 8];

  int t = threadIdx.x;
  int lane = t & 63, wave = t >> 6;
  int wm = wave >> 1, wn = wave & 1;
  int lrow = lane & 15, lgrp = lane >> 4;
  int m0 = blockIdx.y * 128, n0 = blockIdx.x * 128;

  // staging: chunk = 16 rows x 32 cols = 1024B; lane covers row lane>>2,
  // 16B at col (lane&3)*8. wave w stages chunks w (rows w*16) and w+4 (+64).
  int srow = lane >> 2, scol = (lane & 3) * 8;
  const short* gA  = A + (size_t)(m0 + wave * 16 + srow) * K + scol;
  const short* gB  = B + (size_t)(n0 + wave * 16 + srow) * K + scol;
  const short* gB2 = DUAL ? B + (size_t)(4096 + n0 + wave * 16 + srow) * K + scol
                          : (const short*)nullptr;

  f32x4 acc[4][4];
  f32x4 acc2[4][4];
  const f32x4 zero = { 0.f, 0.f, 0.f, 0.f };
#pragma unroll
  for (int i = 0; i < 4; i++)
#pragma unroll
    for (int j = 0; j < 4; j++) { acc[i][j] = zero; if (DUAL) acc2[i][j] = zero; }

  for (int k0 = 0; k0 < K; k0 += 32) {
    gload16(gA + k0,                    As + wave * 512);
    gload16(gA + (size_t)64 * K + k0,   As + (wave + 4) * 512);
    gload16(gB + k0,                    Bs + wave * 512);
    gload16(gB + (size_t)64 * K + k0,   Bs + (wave + 4) * 512);
    if (DUAL) {
      gload16(gB2 + k0,                  Bs2 + wave * 512);
      gload16(gB2 + (size_t)64 * K + k0, Bs2 + (wave + 4) * 512);
    }
    __syncthreads();   // vmcnt(0) drain + barrier: tiles ready

    bf16x8 af[4], bfr[4], bfr2[4];
#pragma unroll
    for (int mf = 0; mf < 4; mf++)
      af[mf] = *(const bf16x8*)&As[(wm * 64 + mf * 16 + lrow) * 32 + lgrp * 8];
#pragma unroll
    for (int nf = 0; nf < 4; nf++)
      bfr[nf] = *(const bf16x8*)&Bs[(wn * 64 + nf * 16 + lrow) * 32 + lgrp * 8];
    if (DUAL) {
#pragma unroll
      for (int nf = 0; nf < 4; nf++)
        bfr2[nf] = *(const bf16x8*)&Bs2[(wn * 64 + nf * 16 + lrow) * 32 + lgrp * 8];
    }
#pragma unroll
    for (int mf = 0; mf < 4; mf++)
#pragma unroll
      for (int nf = 0; nf < 4; nf++) {
        acc[mf][nf] = __builtin_amdgcn_mfma_f32_16x16x32_bf16(af[mf], bfr[nf], acc[mf][nf], 0, 0, 0);
        if (DUAL)
          acc2[mf][nf] = __builtin_amdgcn_mfma_f32_16x16x32_bf16(af[mf], bfr2[nf], acc2[mf][nf], 0, 0, 0);
      }
    __syncthreads();   // all waves done reading before next stage overwrites
  }

#pragma unroll
  for (int mf = 0; mf < 4; mf++)
#pragma unroll
    for (int nf = 0; nf < 4; nf++)
#pragma unroll
      for (int r = 0; r < 4; r++) {
        int row = m0 + wm * 64 + mf * 16 + lgrp * 4 + r;
        int col = n0 + wn * 64 + nf * 16 + lrow;
        float v = acc[mf][nf][r];
        if (EPI == 0) {
          out16[(size_t)row * N + col] = f2b(v * scale);
        } else if (EPI == 1) {
          out32[(size_t)row * N + col] = v + res[(size_t)row * N + col];
        } else {
          float gate = acc2[mf][nf][r];
          float sig = 1.0f / (1.0f + __expf(-gate));
          out16[(size_t)row * N + col] = f2b(v * gate * sig);
        }
      }
}

// ------------------------------- Attention ---------------------------------
// MQA flash attention. Grid (16 q-tiles, B*H=64). 1 wave/block.
__global__ __launch_bounds__(64) void attn_kernel(const short* __restrict__ q,
                                                  const short* __restrict__ kv,
                                                  short* __restrict__ ao)
{
  __shared__ short Ks[64 * 64];   // [kv][d]
  __shared__ short Vs[64 * 64];   // transposed: [d][kv]
  __shared__ short Ps[64 * 64];   // [q][kv]

  int lane = threadIdx.x;
  int lrow = lane & 15, lgrp = lane >> 4;
  int qt = blockIdx.x, bh = blockIdx.y;
  int b = bh >> 4, h = bh & 15;

  bf16x8 qf[4][2];
  const short* qb = q + ((size_t)(b * 1024 + qt * 64)) * 1024 + h * 64;
#pragma unroll
  for (int mf = 0; mf < 4; mf++)
#pragma unroll
    for (int kk = 0; kk < 2; kk++)
      qf[mf][kk] = *(const bf16x8*)&qb[(size_t)(mf * 16 + lrow) * 1024 + kk * 32 + lgrp * 8];

  f32x4 oacc[4][4];
  float m_[4][4], l_[4][4];
  const f32x4 zero = { 0.f, 0.f, 0.f, 0.f };
#pragma unroll
  for (int i = 0; i < 4; i++)
#pragma unroll
    for (int j = 0; j < 4; j++) {
      oacc[i][j] = zero; m_[i][j] = -3.0e38f; l_[i][j] = 0.f;
    }

  for (int j0 = 0; j0 < 1024; j0 += 64) {
    __syncthreads();
    {
      const short* kvb = kv + ((size_t)(b * 1024 + j0 + lane)) * 128;
#pragma unroll
      for (int c = 0; c < 64; c += 8) {
        *(int4*)&Ks[lane * 64 + c] = *(const int4*)&kvb[c];
        int4 vv = *(const int4*)&kvb[64 + c];
        const short* vs = (const short*)&vv;
#pragma unroll
        for (int i = 0; i < 8; i++) Vs[(c + i) * 64 + lane] = vs[i];
      }
    }
    __syncthreads();

    f32x4 sacc[4][4];
#pragma unroll
    for (int i = 0; i < 4; i++)
#pragma unroll
      for (int j = 0; j < 4; j++) sacc[i][j] = zero;

    bf16x8 kf[4][2];
#pragma unroll
    for (int nf = 0; nf < 4; nf++)
#pragma unroll
      for (int kk = 0; kk < 2; kk++)
        kf[nf][kk] = *(const bf16x8*)&Ks[(nf * 16 + lrow) * 64 + kk * 32 + lgrp * 8];
#pragma unroll
    for (int mf = 0; mf < 4; mf++)
#pragma unroll
      for (int nf = 0; nf < 4; nf++)
#pragma unroll
        for (int kk = 0; kk < 2; kk++)
          sacc[mf][nf] = __builtin_amdgcn_mfma_f32_16x16x32_bf16(qf[mf][kk], kf[nf][kk], sacc[mf][nf], 0, 0, 0);

#pragma unroll
    for (int mf = 0; mf < 4; mf++)
#pragma unroll
      for (int r = 0; r < 4; r++) {
        float mx = fmaxf(fmaxf(sacc[mf][0][r], sacc[mf][1][r]),
                         fmaxf(sacc[mf][2][r], sacc[mf][3][r]));
#pragma unroll
        for (int o = 8; o >= 1; o >>= 1) mx = fmaxf(mx, __shfl_xor(mx, o));
        float mnew = fmaxf(m_[mf][r], mx);
        float corr = __expf(m_[mf][r] - mnew);
        float rs = 0.f;
#pragma unroll
        for (int nf = 0; nf < 4; nf++) {
          float p = __expf(sacc[mf][nf][r] - mnew);
          sacc[mf][nf][r] = p;
          rs += p;
        }
#pragma unroll
        for (int o = 8; o >= 1; o >>= 1) rs += __shfl_xor(rs, o);
        l_[mf][r] = l_[mf][r] * corr + rs;
        m_[mf][r] = mnew;
#pragma unroll
        for (int nf = 0; nf < 4; nf++) {
          oacc[mf][nf][r] *= corr;
          Ps[(mf * 16 + lgrp * 4 + r) * 64 + nf * 16 + lrow] = f2b(sacc[mf][nf][r]);
        }
      }
    __syncthreads();

    bf16x8 vf[4][2];
#pragma unroll
    for (int nf = 0; nf < 4; nf++)
#pragma unroll
      for (int kk = 0; kk < 2; kk++)
        vf[nf][kk] = *(const bf16x8*)&Vs[(nf * 16 + lrow) * 64 + kk * 32 + lgrp * 8];
#pragma unroll
    for (int mf = 0; mf < 4; mf++) {
      bf16x8 pf[2];
#pragma unroll
      for (int kk = 0; kk < 2; kk++)
        pf[kk] = *(const bf16x8*)&Ps[(mf * 16 + lrow) * 64 + kk * 32 + lgrp * 8];
#pragma unroll
      for (int nf = 0; nf < 4; nf++)
#pragma unroll
        for (int kk = 0; kk < 2; kk++)
          oacc[mf][nf] = __builtin_amdgcn_mfma_f32_16x16x32_bf16(pf[kk], vf[nf][kk], oacc[mf][nf], 0, 0, 0);
    }
  }

#pragma unroll
  for (int mf = 0; mf < 4; mf++)
#pragma unroll
    for (int nf = 0; nf < 4; nf++)
#pragma unroll
      for (int r = 0; r < 4; r++) {
        int qrow = qt * 64 + mf * 16 + lgrp * 4 + r;
        float val = oacc[mf][nf][r] / l_[mf][r];
        ao[((size_t)(b * 1024 + qrow)) * 1024 + h * 64 + nf * 16 + lrow] = f2b(val);
      }
}

// ------------------------------- launcher ----------------------------------
extern "C" void kernel_launch(void* const* d_in, const int* in_sizes, int n_in,
                              void* d_out, int out_size, void* d_ws, size_t ws_size,
                              hipStream_t stream) {
  const float* x     = (const float*)d_in[0];
  const float* y     = (const float*)d_in[1];
  const float* g1    = (const float*)d_in[2];
  const float* g2    = (const float*)d_in[3];
  const float* g_out = (const float*)d_in[4];
  const float* Wq    = (const float*)d_in[5];
  const float* Wkv   = (const float*)d_in[6];
  const float* Wo    = (const float*)d_in[7];
  const float* Wff1  = (const float*)d_in[8];
  const float* Wff2  = (const float*)d_in[9];

  char* ws = (char*)d_ws;
  size_t off = 0;
  auto alloc = [&](size_t bytes) { char* p = ws + off; off += bytes; return p; };
  short* wqT    = (short*)alloc((size_t)1024 * 1024 * 2);   // [1024][1024]
  short* wkvT   = (short*)alloc((size_t)128 * 1024 * 2);    // [128][1024]
  short* woT    = (short*)alloc((size_t)1024 * 1024 * 2);   // [1024][1024]
  short* wff1T  = (short*)alloc((size_t)8192 * 1024 * 2);   // [8192][1024]
  short* wff2T  = (short*)alloc((size_t)1024 * 4096 * 2);   // [1024][4096]
  short* xn16   = (short*)alloc((size_t)4096 * 1024 * 2);
  short* yn16   = (short*)alloc((size_t)4096 * 1024 * 2);
  float* ynf    = (float*)alloc((size_t)4096 * 1024 * 4);
  short* q16    = (short*)alloc((size_t)4096 * 1024 * 2);
  short* kv16   = (short*)alloc((size_t)4096 * 128 * 2);
  short* ao16   = (short*)alloc((size_t)4096 * 1024 * 2);
  float* lnout  = (float*)alloc((size_t)4096 * 1024 * 4);
  short* act16  = (short*)alloc((size_t)4096 * 4096 * 2);
  float* outf   = (float*)d_out;

  // weight transpose-convert: [K][N] f32 -> [N][K] bf16
  cvtT_kernel<<<dim3(1024 / 32, 1024 / 32), 256, 0, stream>>>(Wq,   wqT,   1024, 1024);
  cvtT_kernel<<<dim3(128 / 32, 1024 / 32),  256, 0, stream>>>(Wkv,  wkvT,  1024, 128);
  cvtT_kernel<<<dim3(1024 / 32, 1024 / 32), 256, 0, stream>>>(Wo,   woT,   1024, 1024);
  cvtT_kernel<<<dim3(8192 / 32, 1024 / 32), 256, 0, stream>>>(Wff1, wff1T, 1024, 8192);
  cvtT_kernel<<<dim3(1024 / 32, 4096 / 32), 256, 0, stream>>>(Wff2, wff2T, 4096, 1024);

  // LayerNorms
  ln_kernel<<<4096, 256, 0, stream>>>(x, g1, xn16, nullptr);
  ln_kernel<<<4096, 256, 0, stream>>>(y, g2, yn16, ynf);

  // q = (xn @ Wq) * 1/8    kv = yn @ Wkv
  gemm_kernel<0, false><<<dim3(8, 32), 256, 0, stream>>>(
      xn16, wqT, 4096, 1024, 1024, q16, nullptr, nullptr, 0.125f);
  gemm_kernel<0, false><<<dim3(1, 32), 256, 0, stream>>>(
      yn16, wkvT, 4096, 128, 1024, kv16, nullptr, nullptr, 1.0f);

  // attention
  attn_kernel<<<dim3(16, 64), 64, 0, stream>>>(q16, kv16, ao16);

  // out = attn @ Wo + yn   (f32, into d_out as scratch)
  gemm_kernel<1, false><<<dim3(8, 32), 256, 0, stream>>>(
      ao16, woT, 4096, 1024, 1024, nullptr, outf, ynf, 1.0f);

  // ln_out = LN(out) * g_out  (f32)
  ln_kernel<<<4096, 256, 0, stream>>>(outf, g_out, nullptr, lnout);

  // act = silu(gate) * val   (fused dual-B GEMM over Wff1^T)
  gemm_kernel<2, true><<<dim3(32, 32), 256, 0, stream>>>(
      yn16, wff1T, 4096, 4096, 1024, act16, nullptr, nullptr, 1.0f);

  // d_out = act @ Wff2 + ln_out
  gemm_kernel<1, false><<<dim3(8, 32), 256, 0, stream>>>(
      act16, wff2T, 4096, 1024, 4096, nullptr, outf, lnout, 1.0f);
}

// Round 3
// 422.252 us; speedup vs baseline: 2.1068x; 1.2433x over previous
//
#include <hip/hip_runtime.h>
#include <hip/hip_bf16.h>

// ---------------------------------------------------------------------------
// MQ Parallel-FF Transformer block, MI355X (gfx950)
// Round 2: 2-phase double-buffered GEMM (T3 minimum recipe);
//          attention: 4 waves/block sharing K/V tiles (MQA), setprio.
// ---------------------------------------------------------------------------

typedef __attribute__((ext_vector_type(8))) short bf16x8;   // 8 bf16 (4 VGPR)
typedef __attribute__((ext_vector_type(4))) short s16x4;
typedef __attribute__((ext_vector_type(4))) float f32x4;

__device__ __forceinline__ short f2b(float f) {
  union { float f; unsigned u; } v; v.f = f;
  unsigned r = (v.u + 0x7fffu + ((v.u >> 16) & 1u)) >> 16;
  return (short)r;
}

__device__ __forceinline__ void gload16(const short* g, short* l) {
  __builtin_amdgcn_global_load_lds(
      (const __attribute__((address_space(1))) void*)g,
      (__attribute__((address_space(3))) void*)l, 16, 0, 0);
}

// ---------------- f32 [K][N] -> bf16 [N][K] transpose-convert ---------------
__global__ __launch_bounds__(256) void cvtT_kernel(const float* __restrict__ in,
                                                   short* __restrict__ out,
                                                   int K, int N) {
  __shared__ float tile[32][33];
  int n0 = blockIdx.x * 32, k0 = blockIdx.y * 32;
  int tx = threadIdx.x & 7, ty = threadIdx.x >> 3;     // 8 x 32
  float4 v = *(const float4*)&in[(size_t)(k0 + ty) * N + n0 + tx * 4];
  tile[ty][tx * 4 + 0] = v.x;
  tile[ty][tx * 4 + 1] = v.y;
  tile[ty][tx * 4 + 2] = v.z;
  tile[ty][tx * 4 + 3] = v.w;
  __syncthreads();
  s16x4 o = { f2b(tile[tx * 4 + 0][ty]), f2b(tile[tx * 4 + 1][ty]),
              f2b(tile[tx * 4 + 2][ty]), f2b(tile[tx * 4 + 3][ty]) };
  *(s16x4*)&out[(size_t)(n0 + ty) * K + k0 + tx * 4] = o;
}

// --------------------------------- LayerNorm -------------------------------
__global__ __launch_bounds__(256) void ln_kernel(const float* __restrict__ in,
                                                 const float* __restrict__ gamma,
                                                 short* __restrict__ out16,
                                                 float* __restrict__ out32) {
  int row = blockIdx.x;
  int t = threadIdx.x;
  float4 v = ((const float4*)(in + (size_t)row * 1024))[t];
  float s  = v.x + v.y + v.z + v.w;
  float sq = v.x*v.x + v.y*v.y + v.z*v.z + v.w*v.w;
  __shared__ float ssum[256], ssq[256];
  ssum[t] = s; ssq[t] = sq;
  __syncthreads();
  for (int o = 128; o > 0; o >>= 1) {
    if (t < o) { ssum[t] += ssum[t + o]; ssq[t] += ssq[t + o]; }
    __syncthreads();
  }
  float mu  = ssum[0] * (1.0f / 1024.0f);
  float var = ssq[0] * (1.0f / 1024.0f) - mu * mu;
  float rs  = rsqrtf(var + 1e-5f);
  float4 g = ((const float4*)gamma)[t];
  float o0 = (v.x - mu) * rs * g.x;
  float o1 = (v.y - mu) * rs * g.y;
  float o2 = (v.z - mu) * rs * g.z;
  float o3 = (v.w - mu) * rs * g.w;
  if (out16) {
    s16x4 o = { f2b(o0), f2b(o1), f2b(o2), f2b(o3) };
    ((s16x4*)out16)[(size_t)row * 256 + t] = o;
  }
  if (out32) {
    float4 o = { o0, o1, o2, o3 };
    ((float4*)out32)[(size_t)row * 256 + t] = o;
  }
}

// ----------------------------------- GEMM ----------------------------------
// C[M,N] = A[M,K] @ B^T   where B is stored [N][K] bf16 (K-contiguous).
// 128x128 tile, BK=32, 256 threads (4 waves, 2x2), 16x16x32 bf16 MFMA.
// 2-phase double-buffered: STAGE(next) issued before compute(cur); one
// vmcnt(0) + s_barrier per K-step.
// EPI 0: out16 = bf16(acc*scale)
// EPI 1: out32 = acc + res                       (f32)
// EPI 2 (DUAL): out16 = bf16(silu(acc2)*acc)     acc2 uses B rows +4096
template<int EPI, bool DUAL>
__global__ __launch_bounds__(256) void gemm_kernel(
    const short* __restrict__ A, const short* __restrict__ B,
    int M, int N, int K,
    short* __restrict__ out16, float* __restrict__ out32,
    const float* __restrict__ res, float scale)
{
  __shared__ __align__(16) short As[2][128 * 32];
  __shared__ __align__(16) short Bs[2][128 * 32];
  __shared__ __align__(16) short Bs2[DUAL ? 2 : 1][DUAL ? 128 * 32 : 8];

  int t = threadIdx.x;
  int lane = t & 63, wave = t >> 6;
  int wm = wave >> 1, wn = wave & 1;
  int lrow = lane & 15, lgrp = lane >> 4;
  int m0 = blockIdx.y * 128, n0 = blockIdx.x * 128;

  // staging: wave w covers rows [w*16, w*16+16) and [64+w*16, ...).
  // lane l: row w*16 + (l>>2), 16B at col (l&3)*8.  LDS dest linear.
  int srow = lane >> 2, scol = (lane & 3) * 8;
  const short* gA  = A + (size_t)(m0 + wave * 16 + srow) * K + scol;
  const short* gB  = B + (size_t)(n0 + wave * 16 + srow) * K + scol;
  const short* gB2 = DUAL ? B + (size_t)(4096 + n0 + wave * 16 + srow) * K + scol : gB;

  auto STAGE = [&](int buf, int k0) {
    gload16(gA + k0,                  &As[buf][wave * 512]);
    gload16(gA + (size_t)64 * K + k0, &As[buf][(wave + 4) * 512]);
    gload16(gB + k0,                  &Bs[buf][wave * 512]);
    gload16(gB + (size_t)64 * K + k0, &Bs[buf][(wave + 4) * 512]);
    if constexpr (DUAL) {
      gload16(gB2 + k0,                  &Bs2[buf][wave * 512]);
      gload16(gB2 + (size_t)64 * K + k0, &Bs2[buf][(wave + 4) * 512]);
    }
  };

  f32x4 acc[4][4];
  f32x4 acc2[4][4];
  const f32x4 zero = { 0.f, 0.f, 0.f, 0.f };
#pragma unroll
  for (int i = 0; i < 4; i++)
#pragma unroll
    for (int j = 0; j < 4; j++) { acc[i][j] = zero; if (DUAL) acc2[i][j] = zero; }

  STAGE(0, 0);
  asm volatile("s_waitcnt vmcnt(0)" ::: "memory");
  __builtin_amdgcn_s_barrier();

  int nt = K / 32, cur = 0;
  for (int tI = 0; tI < nt; ++tI) {
    if (tI + 1 < nt) STAGE(cur ^ 1, (tI + 1) * 32);

    bf16x8 af[4], bfr[4], bfr2[4];
#pragma unroll
    for (int mf = 0; mf < 4; mf++)
      af[mf] = *(const bf16x8*)&As[cur][(wm * 64 + mf * 16 + lrow) * 32 + lgrp * 8];
#pragma unroll
    for (int nf = 0; nf < 4; nf++)
      bfr[nf] = *(const bf16x8*)&Bs[cur][(wn * 64 + nf * 16 + lrow) * 32 + lgrp * 8];
    if constexpr (DUAL) {
#pragma unroll
      for (int nf = 0; nf < 4; nf++)
        bfr2[nf] = *(const bf16x8*)&Bs2[cur][(wn * 64 + nf * 16 + lrow) * 32 + lgrp * 8];
    }
    // reads of buf[cur] must complete before next iter's STAGE overwrites it
    asm volatile("s_waitcnt lgkmcnt(0)" ::: "memory");
    __builtin_amdgcn_sched_barrier(0);

#pragma unroll
    for (int mf = 0; mf < 4; mf++)
#pragma unroll
      for (int nf = 0; nf < 4; nf++) {
        acc[mf][nf] = __builtin_amdgcn_mfma_f32_16x16x32_bf16(af[mf], bfr[nf], acc[mf][nf], 0, 0, 0);
        if constexpr (DUAL)
          acc2[mf][nf] = __builtin_amdgcn_mfma_f32_16x16x32_bf16(af[mf], bfr2[nf], acc2[mf][nf], 0, 0, 0);
      }

    // next tile's loads landed; all waves done reading buf[cur]
    asm volatile("s_waitcnt vmcnt(0)" ::: "memory");
    __builtin_amdgcn_s_barrier();
    cur ^= 1;
  }

#pragma unroll
  for (int mf = 0; mf < 4; mf++)
#pragma unroll
    for (int nf = 0; nf < 4; nf++)
#pragma unroll
      for (int r = 0; r < 4; r++) {
        int row = m0 + wm * 64 + mf * 16 + lgrp * 4 + r;
        int col = n0 + wn * 64 + nf * 16 + lrow;
        float v = acc[mf][nf][r];
        if (EPI == 0) {
          out16[(size_t)row * N + col] = f2b(v * scale);
        } else if (EPI == 1) {
          out32[(size_t)row * N + col] = v + res[(size_t)row * N + col];
        } else {
          float gate = acc2[mf][nf][r];
          float sig = 1.0f / (1.0f + __expf(-gate));
          out16[(size_t)row * N + col] = f2b(v * gate * sig);
        }
      }
}

// ------------------------------- Attention ---------------------------------
// MQA flash attention, 4 waves/block sharing K/V (K/V identical across heads).
// Grid (16 q-tiles, b*4+headgroup = 16). wave w -> head hg*4+w.
__global__ __launch_bounds__(256) void attn_kernel(const short* __restrict__ q,
                                                   const short* __restrict__ kv,
                                                   short* __restrict__ ao)
{
  __shared__ short Ks[64 * 64];      // [kv][d]
  __shared__ short Vs[64 * 64];      // transposed: [d][kv]
  __shared__ short Ps[4][64 * 64];   // per-wave [q][kv]

  int t = threadIdx.x;
  int lane = t & 63, wave = t >> 6;
  int lrow = lane & 15, lgrp = lane >> 4;
  int qt = blockIdx.x;
  int b = blockIdx.y >> 2, hg = blockIdx.y & 3;
  int h = hg * 4 + wave;

  bf16x8 qf[4][2];
  const short* qb = q + ((size_t)(b * 1024 + qt * 64)) * 1024 + h * 64;
#pragma unroll
  for (int mf = 0; mf < 4; mf++)
#pragma unroll
    for (int kk = 0; kk < 2; kk++)
      qf[mf][kk] = *(const bf16x8*)&qb[(size_t)(mf * 16 + lrow) * 1024 + kk * 32 + lgrp * 8];

  f32x4 oacc[4][4];
  float m_[4][4], l_[4][4];
  const f32x4 zero = { 0.f, 0.f, 0.f, 0.f };
#pragma unroll
  for (int i = 0; i < 4; i++)
#pragma unroll
    for (int j = 0; j < 4; j++) {
      oacc[i][j] = zero; m_[i][j] = -3.0e38f; l_[i][j] = 0.f;
    }

  for (int j0 = 0; j0 < 1024; j0 += 64) {
    __syncthreads();   // prior PV done reading Ks/Vs
    {
      // wave w covers 32 cols: w<2 -> K half (vector), w>=2 -> V half (transpose)
      const short* kvb = kv + ((size_t)(b * 1024 + j0 + lane)) * 128 + wave * 32;
      int4 d[4];
#pragma unroll
      for (int i = 0; i < 4; i++) d[i] = ((const int4*)kvb)[i];
      if (wave < 2) {
#pragma unroll
        for (int i = 0; i < 4; i++)
          *(int4*)&Ks[lane * 64 + wave * 32 + i * 8] = d[i];
      } else {
        const short* ds = (const short*)d;
#pragma unroll
        for (int i = 0; i < 32; i++)
          Vs[((wave - 2) * 32 + i) * 64 + lane] = ds[i];
      }
    }
    __syncthreads();

    f32x4 sacc[4][4];
#pragma unroll
    for (int i = 0; i < 4; i++)
#pragma unroll
      for (int j = 0; j < 4; j++) sacc[i][j] = zero;

    bf16x8 kf[4][2];
#pragma unroll
    for (int nf = 0; nf < 4; nf++)
#pragma unroll
      for (int kk = 0; kk < 2; kk++)
        kf[nf][kk] = *(const bf16x8*)&Ks[(nf * 16 + lrow) * 64 + kk * 32 + lgrp * 8];
    __builtin_amdgcn_s_setprio(1);
#pragma unroll
    for (int mf = 0; mf < 4; mf++)
#pragma unroll
      for (int nf = 0; nf < 4; nf++)
#pragma unroll
        for (int kk = 0; kk < 2; kk++)
          sacc[mf][nf] = __builtin_amdgcn_mfma_f32_16x16x32_bf16(qf[mf][kk], kf[nf][kk], sacc[mf][nf], 0, 0, 0);
    __builtin_amdgcn_s_setprio(0);

#pragma unroll
    for (int mf = 0; mf < 4; mf++)
#pragma unroll
      for (int r = 0; r < 4; r++) {
        float mx = fmaxf(fmaxf(sacc[mf][0][r], sacc[mf][1][r]),
                         fmaxf(sacc[mf][2][r], sacc[mf][3][r]));
#pragma unroll
        for (int o = 8; o >= 1; o >>= 1) mx = fmaxf(mx, __shfl_xor(mx, o));
        float mnew = fmaxf(m_[mf][r], mx);
        float corr = __expf(m_[mf][r] - mnew);
        float rs = 0.f;
#pragma unroll
        for (int nf = 0; nf < 4; nf++) {
          float p = __expf(sacc[mf][nf][r] - mnew);
          sacc[mf][nf][r] = p;
          rs += p;
        }
#pragma unroll
        for (int o = 8; o >= 1; o >>= 1) rs += __shfl_xor(rs, o);
        l_[mf][r] = l_[mf][r] * corr + rs;
        m_[mf][r] = mnew;
#pragma unroll
        for (int nf = 0; nf < 4; nf++) {
          oacc[mf][nf][r] *= corr;
          Ps[wave][(mf * 16 + lgrp * 4 + r) * 64 + nf * 16 + lrow] = f2b(sacc[mf][nf][r]);
        }
      }
    __syncthreads();

    bf16x8 vf[4][2];
#pragma unroll
    for (int nf = 0; nf < 4; nf++)
#pragma unroll
      for (int kk = 0; kk < 2; kk++)
        vf[nf][kk] = *(const bf16x8*)&Vs[(nf * 16 + lrow) * 64 + kk * 32 + lgrp * 8];
    __builtin_amdgcn_s_setprio(1);
#pragma unroll
    for (int mf = 0; mf < 4; mf++) {
      bf16x8 pf[2];
#pragma unroll
      for (int kk = 0; kk < 2; kk++)
        pf[kk] = *(const bf16x8*)&Ps[wave][(mf * 16 + lrow) * 64 + kk * 32 + lgrp * 8];
#pragma unroll
      for (int nf = 0; nf < 4; nf++)
#pragma unroll
        for (int kk = 0; kk < 2; kk++)
          oacc[mf][nf] = __builtin_amdgcn_mfma_f32_16x16x32_bf16(pf[kk], vf[nf][kk], oacc[mf][nf], 0, 0, 0);
    }
    __builtin_amdgcn_s_setprio(0);
  }

#pragma unroll
  for (int mf = 0; mf < 4; mf++)
#pragma unroll
    for (int nf = 0; nf < 4; nf++)
#pragma unroll
      for (int r = 0; r < 4; r++) {
        int qrow = qt * 64 + mf * 16 + lgrp * 4 + r;
        float val = oacc[mf][nf][r] / l_[mf][r];
        ao[((size_t)(b * 1024 + qrow)) * 1024 + h * 64 + nf * 16 + lrow] = f2b(val);
      }
}

// ------------------------------- launcher ----------------------------------
extern "C" void kernel_launch(void* const* d_in, const int* in_sizes, int n_in,
                              void* d_out, int out_size, void* d_ws, size_t ws_size,
                              hipStream_t stream) {
  const float* x     = (const float*)d_in[0];
  const float* y     = (const float*)d_in[1];
  const float* g1    = (const float*)d_in[2];
  const float* g2    = (const float*)d_in[3];
  const float* g_out = (const float*)d_in[4];
  const float* Wq    = (const float*)d_in[5];
  const float* Wkv   = (const float*)d_in[6];
  const float* Wo    = (const float*)d_in[7];
  const float* Wff1  = (const float*)d_in[8];
  const float* Wff2  = (const float*)d_in[9];

  char* ws = (char*)d_ws;
  size_t off = 0;
  auto alloc = [&](size_t bytes) { char* p = ws + off; off += bytes; return p; };
  short* wqT    = (short*)alloc((size_t)1024 * 1024 * 2);   // [1024][1024]
  short* wkvT   = (short*)alloc((size_t)128 * 1024 * 2);    // [128][1024]
  short* woT    = (short*)alloc((size_t)1024 * 1024 * 2);   // [1024][1024]
  short* wff1T  = (short*)alloc((size_t)8192 * 1024 * 2);   // [8192][1024]
  short* wff2T  = (short*)alloc((size_t)1024 * 4096 * 2);   // [1024][4096]
  short* xn16   = (short*)alloc((size_t)4096 * 1024 * 2);
  short* yn16   = (short*)alloc((size_t)4096 * 1024 * 2);
  float* ynf    = (float*)alloc((size_t)4096 * 1024 * 4);
  short* q16    = (short*)alloc((size_t)4096 * 1024 * 2);
  short* kv16   = (short*)alloc((size_t)4096 * 128 * 2);
  short* ao16   = (short*)alloc((size_t)4096 * 1024 * 2);
  float* lnout  = (float*)alloc((size_t)4096 * 1024 * 4);
  short* act16  = (short*)alloc((size_t)4096 * 4096 * 2);
  float* outf   = (float*)d_out;

  // weight transpose-convert: [K][N] f32 -> [N][K] bf16
  cvtT_kernel<<<dim3(1024 / 32, 1024 / 32), 256, 0, stream>>>(Wq,   wqT,   1024, 1024);
  cvtT_kernel<<<dim3(128 / 32, 1024 / 32),  256, 0, stream>>>(Wkv,  wkvT,  1024, 128);
  cvtT_kernel<<<dim3(1024 / 32, 1024 / 32), 256, 0, stream>>>(Wo,   woT,   1024, 1024);
  cvtT_kernel<<<dim3(8192 / 32, 1024 / 32), 256, 0, stream>>>(Wff1, wff1T, 1024, 8192);
  cvtT_kernel<<<dim3(1024 / 32, 4096 / 32), 256, 0, stream>>>(Wff2, wff2T, 4096, 1024);

  // LayerNorms
  ln_kernel<<<4096, 256, 0, stream>>>(x, g1, xn16, nullptr);
  ln_kernel<<<4096, 256, 0, stream>>>(y, g2, yn16, ynf);

  // q = (xn @ Wq) * 1/8    kv = yn @ Wkv
  gemm_kernel<0, false><<<dim3(8, 32), 256, 0, stream>>>(
      xn16, wqT, 4096, 1024, 1024, q16, nullptr, nullptr, 0.125f);
  gemm_kernel<0, false><<<dim3(1, 32), 256, 0, stream>>>(
      yn16, wkvT, 4096, 128, 1024, kv16, nullptr, nullptr, 1.0f);

  // attention
  attn_kernel<<<dim3(16, 16), 256, 0, stream>>>(q16, kv16, ao16);

  // out = attn @ Wo + yn   (f32, into d_out as scratch)
  gemm_kernel<1, false><<<dim3(8, 32), 256, 0, stream>>>(
      ao16, woT, 4096, 1024, 1024, nullptr, outf, ynf, 1.0f);

  // ln_out = LN(out) * g_out  (f32)
  ln_kernel<<<4096, 256, 0, stream>>>(outf, g_out, nullptr, lnout);

  // act = silu(gate) * val   (fused dual-B GEMM over Wff1^T)
  gemm_kernel<2, true><<<dim3(32, 32), 256, 0, stream>>>(
      yn16, wff1T, 4096, 4096, 1024, act16, nullptr, nullptr, 1.0f);

  // d_out = act @ Wff2 + ln_out
  gemm_kernel<1, false><<<dim3(8, 32), 256, 0, stream>>>(
      act16, wff2T, 4096, 1024, 4096, nullptr, outf, lnout, 1.0f);
}

// Round 4
// 369.353 us; speedup vs baseline: 2.4086x; 1.1432x over previous
//
#include <hip/hip_runtime.h>
#include <hip/hip_bf16.h>

// ---------------------------------------------------------------------------
// MQ Parallel-FF Transformer block, MI355X (gfx950)
// Round 4: ring-buffered GEMM pipeline (depth 4 / 3-dual), BK=32, 128^2 tile,
//          counted vmcnt (never 0 in steady state), one barrier per K-tile.
// ---------------------------------------------------------------------------

typedef __attribute__((ext_vector_type(8))) short bf16x8;   // 8 bf16 (4 VGPR)
typedef __attribute__((ext_vector_type(4))) short s16x4;
typedef __attribute__((ext_vector_type(4))) float f32x4;

__device__ __forceinline__ short f2b(float f) {
  union { float f; unsigned u; } v; v.f = f;
  unsigned r = (v.u + 0x7fffu + ((v.u >> 16) & 1u)) >> 16;
  return (short)r;
}

__device__ __forceinline__ void gload16(const short* g, short* l) {
  __builtin_amdgcn_global_load_lds(
      (const __attribute__((address_space(1))) void*)g,
      (__attribute__((address_space(3))) void*)l, 16, 0, 0);
}

// ---------------- f32 [K][N] -> bf16 [N][K] transpose-convert ---------------
__global__ __launch_bounds__(256) void cvtT_kernel(const float* __restrict__ in,
                                                   short* __restrict__ out,
                                                   int K, int N) {
  __shared__ float tile[32][33];
  int n0 = blockIdx.x * 32, k0 = blockIdx.y * 32;
  int tx = threadIdx.x & 7, ty = threadIdx.x >> 3;     // 8 x 32
  float4 v = *(const float4*)&in[(size_t)(k0 + ty) * N + n0 + tx * 4];
  tile[ty][tx * 4 + 0] = v.x;
  tile[ty][tx * 4 + 1] = v.y;
  tile[ty][tx * 4 + 2] = v.z;
  tile[ty][tx * 4 + 3] = v.w;
  __syncthreads();
  s16x4 o = { f2b(tile[tx * 4 + 0][ty]), f2b(tile[tx * 4 + 1][ty]),
              f2b(tile[tx * 4 + 2][ty]), f2b(tile[tx * 4 + 3][ty]) };
  *(s16x4*)&out[(size_t)(n0 + ty) * K + k0 + tx * 4] = o;
}

// --------------------------------- LayerNorm -------------------------------
__global__ __launch_bounds__(256) void ln_kernel(const float* __restrict__ in,
                                                 const float* __restrict__ gamma,
                                                 short* __restrict__ out16,
                                                 float* __restrict__ out32) {
  int row = blockIdx.x;
  int t = threadIdx.x;
  float4 v = ((const float4*)(in + (size_t)row * 1024))[t];
  float s  = v.x + v.y + v.z + v.w;
  float sq = v.x*v.x + v.y*v.y + v.z*v.z + v.w*v.w;
  __shared__ float ssum[256], ssq[256];
  ssum[t] = s; ssq[t] = sq;
  __syncthreads();
  for (int o = 128; o > 0; o >>= 1) {
    if (t < o) { ssum[t] += ssum[t + o]; ssq[t] += ssq[t + o]; }
    __syncthreads();
  }
  float mu  = ssum[0] * (1.0f / 1024.0f);
  float var = ssq[0] * (1.0f / 1024.0f) - mu * mu;
  float rs  = rsqrtf(var + 1e-5f);
  float4 g = ((const float4*)gamma)[t];
  float o0 = (v.x - mu) * rs * g.x;
  float o1 = (v.y - mu) * rs * g.y;
  float o2 = (v.z - mu) * rs * g.z;
  float o3 = (v.w - mu) * rs * g.w;
  if (out16) {
    s16x4 o = { f2b(o0), f2b(o1), f2b(o2), f2b(o3) };
    ((s16x4*)out16)[(size_t)row * 256 + t] = o;
  }
  if (out32) {
    float4 o = { o0, o1, o2, o3 };
    ((float4*)out32)[(size_t)row * 256 + t] = o;
  }
}

// ------------------------------- GEMM (ring) -------------------------------
// C[M,N] = A[M,K] @ B^T   where B is stored [N][K] bf16 (K-contiguous).
// 128x128 tile, BK=32, 256 threads (4 waves, 2x2), 16x16x32 bf16 MFMA.
// Ring of DEPTH K-tile buffers; iteration t stages tile t+DEPTH-1 (slot was
// freed at end of iteration t-1); counted vmcnt keeps 1-2 whole tiles of
// loads in flight across the barrier. One barrier per K-tile.
// EPI 0: out16 = bf16(acc*scale)
// EPI 1: out32 = acc + res                       (f32)
// EPI 2 (DUAL): out16 = bf16(silu(acc2)*acc)     acc2 uses B rows +4096
template<int EPI, bool DUAL>
__global__ __launch_bounds__(256, 2) void gemm_ring(
    const short* __restrict__ A, const short* __restrict__ B,
    int M, int N, int K,
    short* __restrict__ out16, float* __restrict__ out32,
    const float* __restrict__ res, float scale)
{
  constexpr int DEPTH = DUAL ? 3 : 4;   // K-tiles resident
  __shared__ __align__(16) short As[DEPTH][128 * 32];
  __shared__ __align__(16) short Bs[DEPTH][128 * 32];
  __shared__ __align__(16) short Bs2[DUAL ? DEPTH : 1][DUAL ? 128 * 32 : 8];

  int t = threadIdx.x;
  int lane = t & 63, wave = t >> 6;
  int wm = wave >> 1, wn = wave & 1;
  int lrow = lane & 15, lgrp = lane >> 4;
  int m0 = blockIdx.y * 128, n0 = blockIdx.x * 128;

  // staging: wave w covers rows [w*16, w*16+16) and [64+w*16, ...).
  // LDS dest is wave-uniform base; HW adds lane*16B (= row l>>2, col (l&3)*8).
  int srow = lane >> 2, scol = (lane & 3) * 8;
  const short* gA  = A + (size_t)(m0 + wave * 16 + srow) * K + scol;
  const short* gB  = B + (size_t)(n0 + wave * 16 + srow) * K + scol;
  const short* gB2 = DUAL ? B + (size_t)(4096 + n0 + wave * 16 + srow) * K + scol : gB;

  auto STAGE = [&](int slot, int kt) {
    int k0 = kt * 32;
    gload16(gA + k0,                  &As[slot][wave * 512]);
    gload16(gA + (size_t)64 * K + k0, &As[slot][(wave + 4) * 512]);
    gload16(gB + k0,                  &Bs[slot][wave * 512]);
    gload16(gB + (size_t)64 * K + k0, &Bs[slot][(wave + 4) * 512]);
    if constexpr (DUAL) {
      gload16(gB2 + k0,                  &Bs2[slot][wave * 512]);
      gload16(gB2 + (size_t)64 * K + k0, &Bs2[slot][(wave + 4) * 512]);
    }
  };

  f32x4 acc[4][4];
  f32x4 acc2[4][4];
  const f32x4 zero = { 0.f, 0.f, 0.f, 0.f };
#pragma unroll
  for (int i = 0; i < 4; i++)
#pragma unroll
    for (int j = 0; j < 4; j++) { acc[i][j] = zero; if (DUAL) acc2[i][j] = zero; }

  int nt = K / 32;
  // prologue: fill DEPTH-1 slots
#pragma unroll
  for (int p = 0; p < DEPTH - 1; p++) STAGE(p, p);

  int slot = 0, stage_slot = (DEPTH - 1) % DEPTH;
  for (int tI = 0; tI < nt; ++tI) {
    // wait for tile tI: keep newer tiles' loads in flight (never drain to 0
    // mid-loop). Per-wave loads per tile: DUAL?6:4.
    int rem = nt - 1 - tI;
    if constexpr (DUAL) {
      if (rem >= 1) asm volatile("s_waitcnt vmcnt(6)" ::: "memory");
      else          asm volatile("s_waitcnt vmcnt(0)" ::: "memory");
    } else {
      if (rem >= 2)      asm volatile("s_waitcnt vmcnt(8)" ::: "memory");
      else if (rem == 1) asm volatile("s_waitcnt vmcnt(4)" ::: "memory");
      else               asm volatile("s_waitcnt vmcnt(0)" ::: "memory");
    }
    __builtin_amdgcn_s_barrier();

    // stage tile tI+DEPTH-1 into the slot freed at end of iteration tI-1
    if (tI + DEPTH - 1 < nt) STAGE(stage_slot, tI + DEPTH - 1);

    bf16x8 af[4], bfr[4], bfr2[4];
#pragma unroll
    for (int mf = 0; mf < 4; mf++)
      af[mf] = *(const bf16x8*)&As[slot][(wm * 64 + mf * 16 + lrow) * 32 + lgrp * 8];
#pragma unroll
    for (int nf = 0; nf < 4; nf++)
      bfr[nf] = *(const bf16x8*)&Bs[slot][(wn * 64 + nf * 16 + lrow) * 32 + lgrp * 8];
    if constexpr (DUAL) {
#pragma unroll
      for (int nf = 0; nf < 4; nf++)
        bfr2[nf] = *(const bf16x8*)&Bs2[slot][(wn * 64 + nf * 16 + lrow) * 32 + lgrp * 8];
    }
    asm volatile("s_waitcnt lgkmcnt(0)" ::: "memory");
    __builtin_amdgcn_sched_barrier(0);

    __builtin_amdgcn_s_setprio(1);
#pragma unroll
    for (int mf = 0; mf < 4; mf++)
#pragma unroll
      for (int nf = 0; nf < 4; nf++) {
        acc[mf][nf] = __builtin_amdgcn_mfma_f32_16x16x32_bf16(af[mf], bfr[nf], acc[mf][nf], 0, 0, 0);
        if constexpr (DUAL)
          acc2[mf][nf] = __builtin_amdgcn_mfma_f32_16x16x32_bf16(af[mf], bfr2[nf], acc2[mf][nf], 0, 0, 0);
      }
    __builtin_amdgcn_s_setprio(0);

    slot = (slot + 1 == DEPTH) ? 0 : slot + 1;
    stage_slot = (stage_slot + 1 == DEPTH) ? 0 : stage_slot + 1;
  }

#pragma unroll
  for (int mf = 0; mf < 4; mf++)
#pragma unroll
    for (int nf = 0; nf < 4; nf++)
#pragma unroll
      for (int r = 0; r < 4; r++) {
        int row = m0 + wm * 64 + mf * 16 + lgrp * 4 + r;
        int col = n0 + wn * 64 + nf * 16 + lrow;
        float v = acc[mf][nf][r];
        if (EPI == 0) {
          out16[(size_t)row * N + col] = f2b(v * scale);
        } else if (EPI == 1) {
          out32[(size_t)row * N + col] = v + res[(size_t)row * N + col];
        } else {
          float gate = acc2[mf][nf][r];
          float sig = 1.0f / (1.0f + __expf(-gate));
          out16[(size_t)row * N + col] = f2b(v * gate * sig);
        }
      }
}

// ------------------------------- Attention ---------------------------------
// MQA flash attention, 4 waves/block sharing K/V (K/V identical across heads).
// Grid (16 q-tiles, b*4+headgroup = 16). wave w -> head hg*4+w.
__global__ __launch_bounds__(256) void attn_kernel(const short* __restrict__ q,
                                                   const short* __restrict__ kv,
                                                   short* __restrict__ ao)
{
  __shared__ short Ks[64 * 64];      // [kv][d]
  __shared__ short Vs[64 * 64];      // transposed: [d][kv]
  __shared__ short Ps[4][64 * 64];   // per-wave [q][kv]

  int t = threadIdx.x;
  int lane = t & 63, wave = t >> 6;
  int lrow = lane & 15, lgrp = lane >> 4;
  int qt = blockIdx.x;
  int b = blockIdx.y >> 2, hg = blockIdx.y & 3;
  int h = hg * 4 + wave;

  bf16x8 qf[4][2];
  const short* qb = q + ((size_t)(b * 1024 + qt * 64)) * 1024 + h * 64;
#pragma unroll
  for (int mf = 0; mf < 4; mf++)
#pragma unroll
    for (int kk = 0; kk < 2; kk++)
      qf[mf][kk] = *(const bf16x8*)&qb[(size_t)(mf * 16 + lrow) * 1024 + kk * 32 + lgrp * 8];

  f32x4 oacc[4][4];
  float m_[4][4], l_[4][4];
  const f32x4 zero = { 0.f, 0.f, 0.f, 0.f };
#pragma unroll
  for (int i = 0; i < 4; i++)
#pragma unroll
    for (int j = 0; j < 4; j++) {
      oacc[i][j] = zero; m_[i][j] = -3.0e38f; l_[i][j] = 0.f;
    }

  for (int j0 = 0; j0 < 1024; j0 += 64) {
    __syncthreads();   // prior PV done reading Ks/Vs
    {
      // wave w covers 32 cols: w<2 -> K half (vector), w>=2 -> V half (transpose)
      const short* kvb = kv + ((size_t)(b * 1024 + j0 + lane)) * 128 + wave * 32;
      int4 d[4];
#pragma unroll
      for (int i = 0; i < 4; i++) d[i] = ((const int4*)kvb)[i];
      if (wave < 2) {
#pragma unroll
        for (int i = 0; i < 4; i++)
          *(int4*)&Ks[lane * 64 + wave * 32 + i * 8] = d[i];
      } else {
        const short* ds = (const short*)d;
#pragma unroll
        for (int i = 0; i < 32; i++)
          Vs[((wave - 2) * 32 + i) * 64 + lane] = ds[i];
      }
    }
    __syncthreads();

    f32x4 sacc[4][4];
#pragma unroll
    for (int i = 0; i < 4; i++)
#pragma unroll
      for (int j = 0; j < 4; j++) sacc[i][j] = zero;

    bf16x8 kf[4][2];
#pragma unroll
    for (int nf = 0; nf < 4; nf++)
#pragma unroll
      for (int kk = 0; kk < 2; kk++)
        kf[nf][kk] = *(const bf16x8*)&Ks[(nf * 16 + lrow) * 64 + kk * 32 + lgrp * 8];
    __builtin_amdgcn_s_setprio(1);
#pragma unroll
    for (int mf = 0; mf < 4; mf++)
#pragma unroll
      for (int nf = 0; nf < 4; nf++)
#pragma unroll
        for (int kk = 0; kk < 2; kk++)
          sacc[mf][nf] = __builtin_amdgcn_mfma_f32_16x16x32_bf16(qf[mf][kk], kf[nf][kk], sacc[mf][nf], 0, 0, 0);
    __builtin_amdgcn_s_setprio(0);

#pragma unroll
    for (int mf = 0; mf < 4; mf++)
#pragma unroll
      for (int r = 0; r < 4; r++) {
        float mx = fmaxf(fmaxf(sacc[mf][0][r], sacc[mf][1][r]),
                         fmaxf(sacc[mf][2][r], sacc[mf][3][r]));
#pragma unroll
        for (int o = 8; o >= 1; o >>= 1) mx = fmaxf(mx, __shfl_xor(mx, o));
        float mnew = fmaxf(m_[mf][r], mx);
        float corr = __expf(m_[mf][r] - mnew);
        float rs = 0.f;
#pragma unroll
        for (int nf = 0; nf < 4; nf++) {
          float p = __expf(sacc[mf][nf][r] - mnew);
          sacc[mf][nf][r] = p;
          rs += p;
        }
#pragma unroll
        for (int o = 8; o >= 1; o >>= 1) rs += __shfl_xor(rs, o);
        l_[mf][r] = l_[mf][r] * corr + rs;
        m_[mf][r] = mnew;
#pragma unroll
        for (int nf = 0; nf < 4; nf++) {
          oacc[mf][nf][r] *= corr;
          Ps[wave][(mf * 16 + lgrp * 4 + r) * 64 + nf * 16 + lrow] = f2b(sacc[mf][nf][r]);
        }
      }
    __syncthreads();

    bf16x8 vf[4][2];
#pragma unroll
    for (int nf = 0; nf < 4; nf++)
#pragma unroll
      for (int kk = 0; kk < 2; kk++)
        vf[nf][kk] = *(const bf16x8*)&Vs[(nf * 16 + lrow) * 64 + kk * 32 + lgrp * 8];
    __builtin_amdgcn_s_setprio(1);
#pragma unroll
    for (int mf = 0; mf < 4; mf++) {
      bf16x8 pf[2];
#pragma unroll
      for (int kk = 0; kk < 2; kk++)
        pf[kk] = *(const bf16x8*)&Ps[wave][(mf * 16 + lrow) * 64 + kk * 32 + lgrp * 8];
#pragma unroll
      for (int nf = 0; nf < 4; nf++)
#pragma unroll
        for (int kk = 0; kk < 2; kk++)
          oacc[mf][nf] = __builtin_amdgcn_mfma_f32_16x16x32_bf16(pf[kk], vf[nf][kk], oacc[mf][nf], 0, 0, 0);
    }
    __builtin_amdgcn_s_setprio(0);
  }

#pragma unroll
  for (int mf = 0; mf < 4; mf++)
#pragma unroll
    for (int nf = 0; nf < 4; nf++)
#pragma unroll
      for (int r = 0; r < 4; r++) {
        int qrow = qt * 64 + mf * 16 + lgrp * 4 + r;
        float val = oacc[mf][nf][r] / l_[mf][r];
        ao[((size_t)(b * 1024 + qrow)) * 1024 + h * 64 + nf * 16 + lrow] = f2b(val);
      }
}

// ------------------------------- launcher ----------------------------------
extern "C" void kernel_launch(void* const* d_in, const int* in_sizes, int n_in,
                              void* d_out, int out_size, void* d_ws, size_t ws_size,
                              hipStream_t stream) {
  const float* x     = (const float*)d_in[0];
  const float* y     = (const float*)d_in[1];
  const float* g1    = (const float*)d_in[2];
  const float* g2    = (const float*)d_in[3];
  const float* g_out = (const float*)d_in[4];
  const float* Wq    = (const float*)d_in[5];
  const float* Wkv   = (const float*)d_in[6];
  const float* Wo    = (const float*)d_in[7];
  const float* Wff1  = (const float*)d_in[8];
  const float* Wff2  = (const float*)d_in[9];

  char* ws = (char*)d_ws;
  size_t off = 0;
  auto alloc = [&](size_t bytes) { char* p = ws + off; off += bytes; return p; };
  short* wqT    = (short*)alloc((size_t)1024 * 1024 * 2);   // [1024][1024]
  short* wkvT   = (short*)alloc((size_t)128 * 1024 * 2);    // [128][1024]
  short* woT    = (short*)alloc((size_t)1024 * 1024 * 2);   // [1024][1024]
  short* wff1T  = (short*)alloc((size_t)8192 * 1024 * 2);   // [8192][1024]
  short* wff2T  = (short*)alloc((size_t)1024 * 4096 * 2);   // [1024][4096]
  short* xn16   = (short*)alloc((size_t)4096 * 1024 * 2);
  short* yn16   = (short*)alloc((size_t)4096 * 1024 * 2);
  float* ynf    = (float*)alloc((size_t)4096 * 1024 * 4);
  short* q16    = (short*)alloc((size_t)4096 * 1024 * 2);
  short* kv16   = (short*)alloc((size_t)4096 * 128 * 2);
  short* ao16   = (short*)alloc((size_t)4096 * 1024 * 2);
  float* lnout  = (float*)alloc((size_t)4096 * 1024 * 4);
  short* act16  = (short*)alloc((size_t)4096 * 4096 * 2);
  float* outf   = (float*)d_out;

  // weight transpose-convert: [K][N] f32 -> [N][K] bf16
  cvtT_kernel<<<dim3(1024 / 32, 1024 / 32), 256, 0, stream>>>(Wq,   wqT,   1024, 1024);
  cvtT_kernel<<<dim3(128 / 32, 1024 / 32),  256, 0, stream>>>(Wkv,  wkvT,  1024, 128);
  cvtT_kernel<<<dim3(1024 / 32, 1024 / 32), 256, 0, stream>>>(Wo,   woT,   1024, 1024);
  cvtT_kernel<<<dim3(8192 / 32, 1024 / 32), 256, 0, stream>>>(Wff1, wff1T, 1024, 8192);
  cvtT_kernel<<<dim3(1024 / 32, 4096 / 32), 256, 0, stream>>>(Wff2, wff2T, 4096, 1024);

  // LayerNorms
  ln_kernel<<<4096, 256, 0, stream>>>(x, g1, xn16, nullptr);
  ln_kernel<<<4096, 256, 0, stream>>>(y, g2, yn16, ynf);

  // q = (xn @ Wq) * 1/8    kv = yn @ Wkv
  gemm_ring<0, false><<<dim3(8, 32), 256, 0, stream>>>(
      xn16, wqT, 4096, 1024, 1024, q16, nullptr, nullptr, 0.125f);
  gemm_ring<0, false><<<dim3(1, 32), 256, 0, stream>>>(
      yn16, wkvT, 4096, 128, 1024, kv16, nullptr, nullptr, 1.0f);

  // attention
  attn_kernel<<<dim3(16, 16), 256, 0, stream>>>(q16, kv16, ao16);

  // out = attn @ Wo + yn   (f32, into d_out as scratch)
  gemm_ring<1, false><<<dim3(8, 32), 256, 0, stream>>>(
      ao16, woT, 4096, 1024, 1024, nullptr, outf, ynf, 1.0f);

  // ln_out = LN(out) * g_out  (f32)
  ln_kernel<<<4096, 256, 0, stream>>>(outf, g_out, nullptr, lnout);

  // act = silu(gate) * val   (fused dual-B GEMM over Wff1^T)
  gemm_ring<2, true><<<dim3(32, 32), 256, 0, stream>>>(
      yn16, wff1T, 4096, 4096, 1024, act16, nullptr, nullptr, 1.0f);

  // d_out = act @ Wff2 + ln_out
  gemm_ring<1, false><<<dim3(8, 32), 256, 0, stream>>>(
      act16, wff2T, 4096, 1024, 4096, nullptr, outf, lnout, 1.0f);
}

// Round 5
// 351.716 us; speedup vs baseline: 2.5294x; 1.0501x over previous
//
#include <hip/hip_runtime.h>
#include <hip/hip_bf16.h>

// ---------------------------------------------------------------------------
// MQ Parallel-FF Transformer block, MI355X (gfx950)
// Round 5: attention rework — QBLK=32/wave (512 blocks), XOR-swizzled LDS,
//          async-stage KV prefetch (T14), defer-max (T13), 2 barriers/tile.
//          GEMM ring pipeline unchanged from round 4.
// ---------------------------------------------------------------------------

typedef __attribute__((ext_vector_type(8))) short bf16x8;   // 8 bf16 (4 VGPR)
typedef __attribute__((ext_vector_type(4))) short s16x4;
typedef __attribute__((ext_vector_type(4))) float f32x4;

__device__ __forceinline__ short f2b(float f) {
  union { float f; unsigned u; } v; v.f = f;
  unsigned r = (v.u + 0x7fffu + ((v.u >> 16) & 1u)) >> 16;
  return (short)r;
}

__device__ __forceinline__ void gload16(const short* g, short* l) {
  __builtin_amdgcn_global_load_lds(
      (const __attribute__((address_space(1))) void*)g,
      (__attribute__((address_space(3))) void*)l, 16, 0, 0);
}

// ---------------- f32 [K][N] -> bf16 [N][K] transpose-convert ---------------
__global__ __launch_bounds__(256) void cvtT_kernel(const float* __restrict__ in,
                                                   short* __restrict__ out,
                                                   int K, int N) {
  __shared__ float tile[32][33];
  int n0 = blockIdx.x * 32, k0 = blockIdx.y * 32;
  int tx = threadIdx.x & 7, ty = threadIdx.x >> 3;     // 8 x 32
  float4 v = *(const float4*)&in[(size_t)(k0 + ty) * N + n0 + tx * 4];
  tile[ty][tx * 4 + 0] = v.x;
  tile[ty][tx * 4 + 1] = v.y;
  tile[ty][tx * 4 + 2] = v.z;
  tile[ty][tx * 4 + 3] = v.w;
  __syncthreads();
  s16x4 o = { f2b(tile[tx * 4 + 0][ty]), f2b(tile[tx * 4 + 1][ty]),
              f2b(tile[tx * 4 + 2][ty]), f2b(tile[tx * 4 + 3][ty]) };
  *(s16x4*)&out[(size_t)(n0 + ty) * K + k0 + tx * 4] = o;
}

// --------------------------------- LayerNorm -------------------------------
__global__ __launch_bounds__(256) void ln_kernel(const float* __restrict__ in,
                                                 const float* __restrict__ gamma,
                                                 short* __restrict__ out16,
                                                 float* __restrict__ out32) {
  int row = blockIdx.x;
  int t = threadIdx.x;
  float4 v = ((const float4*)(in + (size_t)row * 1024))[t];
  float s  = v.x + v.y + v.z + v.w;
  float sq = v.x*v.x + v.y*v.y + v.z*v.z + v.w*v.w;
  __shared__ float ssum[256], ssq[256];
  ssum[t] = s; ssq[t] = sq;
  __syncthreads();
  for (int o = 128; o > 0; o >>= 1) {
    if (t < o) { ssum[t] += ssum[t + o]; ssq[t] += ssq[t + o]; }
    __syncthreads();
  }
  float mu  = ssum[0] * (1.0f / 1024.0f);
  float var = ssq[0] * (1.0f / 1024.0f) - mu * mu;
  float rs  = rsqrtf(var + 1e-5f);
  float4 g = ((const float4*)gamma)[t];
  float o0 = (v.x - mu) * rs * g.x;
  float o1 = (v.y - mu) * rs * g.y;
  float o2 = (v.z - mu) * rs * g.z;
  float o3 = (v.w - mu) * rs * g.w;
  if (out16) {
    s16x4 o = { f2b(o0), f2b(o1), f2b(o2), f2b(o3) };
    ((s16x4*)out16)[(size_t)row * 256 + t] = o;
  }
  if (out32) {
    float4 o = { o0, o1, o2, o3 };
    ((float4*)out32)[(size_t)row * 256 + t] = o;
  }
}

// ------------------------------- GEMM (ring) -------------------------------
// C[M,N] = A[M,K] @ B^T   where B is stored [N][K] bf16 (K-contiguous).
// 128x128 tile, BK=32, 256 threads (4 waves, 2x2), 16x16x32 bf16 MFMA.
// Ring of DEPTH K-tile buffers; counted vmcnt keeps tiles in flight across
// the barrier. One barrier per K-tile.
template<int EPI, bool DUAL>
__global__ __launch_bounds__(256, 2) void gemm_ring(
    const short* __restrict__ A, const short* __restrict__ B,
    int M, int N, int K,
    short* __restrict__ out16, float* __restrict__ out32,
    const float* __restrict__ res, float scale)
{
  constexpr int DEPTH = DUAL ? 3 : 4;   // K-tiles resident
  __shared__ __align__(16) short As[DEPTH][128 * 32];
  __shared__ __align__(16) short Bs[DEPTH][128 * 32];
  __shared__ __align__(16) short Bs2[DUAL ? DEPTH : 1][DUAL ? 128 * 32 : 8];

  int t = threadIdx.x;
  int lane = t & 63, wave = t >> 6;
  int wm = wave >> 1, wn = wave & 1;
  int lrow = lane & 15, lgrp = lane >> 4;
  int m0 = blockIdx.y * 128, n0 = blockIdx.x * 128;

  int srow = lane >> 2, scol = (lane & 3) * 8;
  const short* gA  = A + (size_t)(m0 + wave * 16 + srow) * K + scol;
  const short* gB  = B + (size_t)(n0 + wave * 16 + srow) * K + scol;
  const short* gB2 = DUAL ? B + (size_t)(4096 + n0 + wave * 16 + srow) * K + scol : gB;

  auto STAGE = [&](int slot, int kt) {
    int k0 = kt * 32;
    gload16(gA + k0,                  &As[slot][wave * 512]);
    gload16(gA + (size_t)64 * K + k0, &As[slot][(wave + 4) * 512]);
    gload16(gB + k0,                  &Bs[slot][wave * 512]);
    gload16(gB + (size_t)64 * K + k0, &Bs[slot][(wave + 4) * 512]);
    if constexpr (DUAL) {
      gload16(gB2 + k0,                  &Bs2[slot][wave * 512]);
      gload16(gB2 + (size_t)64 * K + k0, &Bs2[slot][(wave + 4) * 512]);
    }
  };

  f32x4 acc[4][4];
  f32x4 acc2[4][4];
  const f32x4 zero = { 0.f, 0.f, 0.f, 0.f };
#pragma unroll
  for (int i = 0; i < 4; i++)
#pragma unroll
    for (int j = 0; j < 4; j++) { acc[i][j] = zero; if (DUAL) acc2[i][j] = zero; }

  int nt = K / 32;
#pragma unroll
  for (int p = 0; p < DEPTH - 1; p++) STAGE(p, p);

  int slot = 0, stage_slot = (DEPTH - 1) % DEPTH;
  for (int tI = 0; tI < nt; ++tI) {
    int rem = nt - 1 - tI;
    if constexpr (DUAL) {
      if (rem >= 1) asm volatile("s_waitcnt vmcnt(6)" ::: "memory");
      else          asm volatile("s_waitcnt vmcnt(0)" ::: "memory");
    } else {
      if (rem >= 2)      asm volatile("s_waitcnt vmcnt(8)" ::: "memory");
      else if (rem == 1) asm volatile("s_waitcnt vmcnt(4)" ::: "memory");
      else               asm volatile("s_waitcnt vmcnt(0)" ::: "memory");
    }
    __builtin_amdgcn_s_barrier();

    if (tI + DEPTH - 1 < nt) STAGE(stage_slot, tI + DEPTH - 1);

    bf16x8 af[4], bfr[4], bfr2[4];
#pragma unroll
    for (int mf = 0; mf < 4; mf++)
      af[mf] = *(const bf16x8*)&As[slot][(wm * 64 + mf * 16 + lrow) * 32 + lgrp * 8];
#pragma unroll
    for (int nf = 0; nf < 4; nf++)
      bfr[nf] = *(const bf16x8*)&Bs[slot][(wn * 64 + nf * 16 + lrow) * 32 + lgrp * 8];
    if constexpr (DUAL) {
#pragma unroll
      for (int nf = 0; nf < 4; nf++)
        bfr2[nf] = *(const bf16x8*)&Bs2[slot][(wn * 64 + nf * 16 + lrow) * 32 + lgrp * 8];
    }
    asm volatile("s_waitcnt lgkmcnt(0)" ::: "memory");
    __builtin_amdgcn_sched_barrier(0);

    __builtin_amdgcn_s_setprio(1);
#pragma unroll
    for (int mf = 0; mf < 4; mf++)
#pragma unroll
      for (int nf = 0; nf < 4; nf++) {
        acc[mf][nf] = __builtin_amdgcn_mfma_f32_16x16x32_bf16(af[mf], bfr[nf], acc[mf][nf], 0, 0, 0);
        if constexpr (DUAL)
          acc2[mf][nf] = __builtin_amdgcn_mfma_f32_16x16x32_bf16(af[mf], bfr2[nf], acc2[mf][nf], 0, 0, 0);
      }
    __builtin_amdgcn_s_setprio(0);

    slot = (slot + 1 == DEPTH) ? 0 : slot + 1;
    stage_slot = (stage_slot + 1 == DEPTH) ? 0 : stage_slot + 1;
  }

#pragma unroll
  for (int mf = 0; mf < 4; mf++)
#pragma unroll
    for (int nf = 0; nf < 4; nf++)
#pragma unroll
      for (int r = 0; r < 4; r++) {
        int row = m0 + wm * 64 + mf * 16 + lgrp * 4 + r;
        int col = n0 + wn * 64 + nf * 16 + lrow;
        float v = acc[mf][nf][r];
        if (EPI == 0) {
          out16[(size_t)row * N + col] = f2b(v * scale);
        } else if (EPI == 1) {
          out32[(size_t)row * N + col] = v + res[(size_t)row * N + col];
        } else {
          float gate = acc2[mf][nf][r];
          float sig = 1.0f / (1.0f + __expf(-gate));
          out16[(size_t)row * N + col] = f2b(v * gate * sig);
        }
      }
}

// ------------------------------- Attention ---------------------------------
// MQA flash attention. QBLK=32 rows per wave; 4 waves/block share swizzled
// K/V tiles (KVBLK=64). Grid (32 q-tiles, b*4+hg = 16). wave w -> head hg*4+w.
// LDS rows are 128B; swizzle: byte ^= ((row&7)<<4).
__global__ __launch_bounds__(256) void attn_kernel(const short* __restrict__ q,
                                                   const short* __restrict__ kv,
                                                   short* __restrict__ ao)
{
  __shared__ __align__(16) short Ks[64 * 64];      // [kv][d]   swizzled
  __shared__ __align__(16) short Vs[64 * 64];      // [d][kv]   swizzled
  __shared__ __align__(16) short Ps[4][32 * 64];   // per-wave [q][kv] swizzled

  int t = threadIdx.x;
  int lane = t & 63, wave = t >> 6;
  int lrow = lane & 15, lgrp = lane >> 4;
  int qt = blockIdx.x;
  int b = blockIdx.y >> 2, hg = blockIdx.y & 3;
  int h = hg * 4 + wave;

  char* Kb = (char*)Ks;
  char* Vb = (char*)Vs;
  char* Pb = (char*)Ps + wave * (32 * 64 * 2);

  bf16x8 qf[2][2];
  const short* qb = q + ((size_t)(b * 1024 + qt * 32)) * 1024 + h * 64;
#pragma unroll
  for (int mf = 0; mf < 2; mf++)
#pragma unroll
    for (int kk = 0; kk < 2; kk++)
      qf[mf][kk] = *(const bf16x8*)&qb[(size_t)(mf * 16 + lrow) * 1024 + kk * 32 + lgrp * 8];

  f32x4 oacc[2][4];
  float m_[2][4], l_[2][4];
  const f32x4 zero = { 0.f, 0.f, 0.f, 0.f };
#pragma unroll
  for (int i = 0; i < 2; i++)
#pragma unroll
    for (int j = 0; j < 4; j++) { oacc[i][j] = zero; }
#pragma unroll
  for (int i = 0; i < 2; i++)
#pragma unroll
    for (int r = 0; r < 4; r++) { m_[i][r] = -3.0e38f; l_[i][r] = 0.f; }

  // prefetch KV tile 0 into regs (lane covers one kv row's 32-short slice)
  int4 d[4];
  {
    const short* kvb = kv + ((size_t)(b * 1024 + lane)) * 128 + wave * 32;
#pragma unroll
    for (int i = 0; i < 4; i++) d[i] = ((const int4*)kvb)[i];
  }

  for (int j0 = 0; j0 < 1024; j0 += 64) {
    __syncthreads();   // all waves done reading Ks/Vs of previous tile
    if (wave < 2) {
      int sw = (lane & 7) << 4;
#pragma unroll
      for (int i = 0; i < 4; i++)
        *(int4*)(Kb + lane * 128 + ((wave * 64 + i * 16) ^ sw)) = d[i];
    } else {
#pragma unroll
      for (int i = 0; i < 4; i++) {
        union { int4 v; short s[8]; } u; u.v = d[i];
#pragma unroll
        for (int j = 0; j < 8; j++) {
          int dd = (wave - 2) * 32 + i * 8 + j;
          *(short*)(Vb + dd * 128 + ((lane * 2) ^ ((dd & 7) << 4))) = u.s[j];
        }
      }
    }
    // async-stage split: issue next tile's loads now, land during compute
    if (j0 + 64 < 1024) {
      const short* kvn = kv + ((size_t)(b * 1024 + j0 + 64 + lane)) * 128 + wave * 32;
#pragma unroll
      for (int i = 0; i < 4; i++) d[i] = ((const int4*)kvn)[i];
    }
    __syncthreads();

    // ---- S = Q @ K^T ----
    bf16x8 kf[4][2];
#pragma unroll
    for (int nf = 0; nf < 4; nf++) {
      int row = nf * 16 + lrow, sw = (row & 7) << 4;
      kf[nf][0] = *(const bf16x8*)(Kb + row * 128 + ((lgrp * 16) ^ sw));
      kf[nf][1] = *(const bf16x8*)(Kb + row * 128 + ((64 + lgrp * 16) ^ sw));
    }
    f32x4 sacc[2][4];
#pragma unroll
    for (int i = 0; i < 2; i++)
#pragma unroll
      for (int j = 0; j < 4; j++) sacc[i][j] = zero;
    __builtin_amdgcn_s_setprio(1);
#pragma unroll
    for (int mf = 0; mf < 2; mf++)
#pragma unroll
      for (int nf = 0; nf < 4; nf++)
#pragma unroll
        for (int kk = 0; kk < 2; kk++)
          sacc[mf][nf] = __builtin_amdgcn_mfma_f32_16x16x32_bf16(qf[mf][kk], kf[nf][kk], sacc[mf][nf], 0, 0, 0);
    __builtin_amdgcn_s_setprio(0);

    // ---- online softmax with defer-max (T13) ----
    float pmax[2][4];
    bool okd = true;
#pragma unroll
    for (int mf = 0; mf < 2; mf++)
#pragma unroll
      for (int r = 0; r < 4; r++) {
        float pm = fmaxf(fmaxf(sacc[mf][0][r], sacc[mf][1][r]),
                         fmaxf(sacc[mf][2][r], sacc[mf][3][r]));
        pmax[mf][r] = pm;
        okd = okd && (pm <= m_[mf][r] + 8.0f);
      }
    if (__all(okd)) {
      // deferred: no max-reduce, no rescale; P bounded by e^8
#pragma unroll
      for (int mf = 0; mf < 2; mf++)
#pragma unroll
        for (int r = 0; r < 4; r++) {
          int row = mf * 16 + lgrp * 4 + r, sw = (row & 7) << 4;
          float al = 0.f;
#pragma unroll
          for (int nf = 0; nf < 4; nf++) {
            float p = __expf(sacc[mf][nf][r] - m_[mf][r]);
            *(short*)(Pb + row * 128 + (((nf * 16 + lrow) * 2) ^ sw)) = f2b(p);
            al += p;
          }
          l_[mf][r] += al;   // lane-partial; reduced once at the end
        }
    } else {
#pragma unroll
      for (int mf = 0; mf < 2; mf++)
#pragma unroll
        for (int r = 0; r < 4; r++) {
          float mx = pmax[mf][r];
#pragma unroll
          for (int o = 8; o >= 1; o >>= 1) mx = fmaxf(mx, __shfl_xor(mx, o));
          float mnew = fmaxf(m_[mf][r], mx);
          float corr = __expf(m_[mf][r] - mnew);
          int row = mf * 16 + lgrp * 4 + r, sw = (row & 7) << 4;
          float al = 0.f;
#pragma unroll
          for (int nf = 0; nf < 4; nf++) {
            float p = __expf(sacc[mf][nf][r] - mnew);
            *(short*)(Pb + row * 128 + (((nf * 16 + lrow) * 2) ^ sw)) = f2b(p);
            al += p;
          }
          l_[mf][r] = l_[mf][r] * corr + al;
          m_[mf][r] = mnew;
#pragma unroll
          for (int nf = 0; nf < 4; nf++) oacc[mf][nf][r] *= corr;
        }
    }

    // ---- O += P @ V ----  (P is wave-private: no barrier needed)
    bf16x8 vf[4][2], pf[2][2];
#pragma unroll
    for (int nf = 0; nf < 4; nf++) {
      int row = nf * 16 + lrow, sw = (row & 7) << 4;
      vf[nf][0] = *(const bf16x8*)(Vb + row * 128 + ((lgrp * 16) ^ sw));
      vf[nf][1] = *(const bf16x8*)(Vb + row * 128 + ((64 + lgrp * 16) ^ sw));
    }
#pragma unroll
    for (int mf = 0; mf < 2; mf++) {
      int row = mf * 16 + lrow, sw = (row & 7) << 4;
      pf[mf][0] = *(const bf16x8*)(Pb + row * 128 + ((lgrp * 16) ^ sw));
      pf[mf][1] = *(const bf16x8*)(Pb + row * 128 + ((64 + lgrp * 16) ^ sw));
    }
    __builtin_amdgcn_s_setprio(1);
#pragma unroll
    for (int mf = 0; mf < 2; mf++)
#pragma unroll
      for (int nf = 0; nf < 4; nf++)
#pragma unroll
        for (int kk = 0; kk < 2; kk++)
          oacc[mf][nf] = __builtin_amdgcn_mfma_f32_16x16x32_bf16(pf[mf][kk], vf[nf][kk], oacc[mf][nf], 0, 0, 0);
    __builtin_amdgcn_s_setprio(0);
  }

  // final l reduction + write
#pragma unroll
  for (int mf = 0; mf < 2; mf++)
#pragma unroll
    for (int r = 0; r < 4; r++) {
      float ls = l_[mf][r];
#pragma unroll
      for (int o = 8; o >= 1; o >>= 1) ls += __shfl_xor(ls, o);
      float inv = 1.0f / ls;
      int qrow = qt * 32 + mf * 16 + lgrp * 4 + r;
#pragma unroll
      for (int nf = 0; nf < 4; nf++) {
        float val = oacc[mf][nf][r] * inv;
        ao[((size_t)(b * 1024 + qrow)) * 1024 + h * 64 + nf * 16 + lrow] = f2b(val);
      }
    }
}

// ------------------------------- launcher ----------------------------------
extern "C" void kernel_launch(void* const* d_in, const int* in_sizes, int n_in,
                              void* d_out, int out_size, void* d_ws, size_t ws_size,
                              hipStream_t stream) {
  const float* x     = (const float*)d_in[0];
  const float* y     = (const float*)d_in[1];
  const float* g1    = (const float*)d_in[2];
  const float* g2    = (const float*)d_in[3];
  const float* g_out = (const float*)d_in[4];
  const float* Wq    = (const float*)d_in[5];
  const float* Wkv   = (const float*)d_in[6];
  const float* Wo    = (const float*)d_in[7];
  const float* Wff1  = (const float*)d_in[8];
  const float* Wff2  = (const float*)d_in[9];

  char* ws = (char*)d_ws;
  size_t off = 0;
  auto alloc = [&](size_t bytes) { char* p = ws + off; off += bytes; return p; };
  short* wqT    = (short*)alloc((size_t)1024 * 1024 * 2);   // [1024][1024]
  short* wkvT   = (short*)alloc((size_t)128 * 1024 * 2);    // [128][1024]
  short* woT    = (short*)alloc((size_t)1024 * 1024 * 2);   // [1024][1024]
  short* wff1T  = (short*)alloc((size_t)8192 * 1024 * 2);   // [8192][1024]
  short* wff2T  = (short*)alloc((size_t)1024 * 4096 * 2);   // [1024][4096]
  short* xn16   = (short*)alloc((size_t)4096 * 1024 * 2);
  short* yn16   = (short*)alloc((size_t)4096 * 1024 * 2);
  float* ynf    = (float*)alloc((size_t)4096 * 1024 * 4);
  short* q16    = (short*)alloc((size_t)4096 * 1024 * 2);
  short* kv16   = (short*)alloc((size_t)4096 * 128 * 2);
  short* ao16   = (short*)alloc((size_t)4096 * 1024 * 2);
  float* lnout  = (float*)alloc((size_t)4096 * 1024 * 4);
  short* act16  = (short*)alloc((size_t)4096 * 4096 * 2);
  float* outf   = (float*)d_out;

  // weight transpose-convert: [K][N] f32 -> [N][K] bf16
  cvtT_kernel<<<dim3(1024 / 32, 1024 / 32), 256, 0, stream>>>(Wq,   wqT,   1024, 1024);
  cvtT_kernel<<<dim3(128 / 32, 1024 / 32),  256, 0, stream>>>(Wkv,  wkvT,  1024, 128);
  cvtT_kernel<<<dim3(1024 / 32, 1024 / 32), 256, 0, stream>>>(Wo,   woT,   1024, 1024);
  cvtT_kernel<<<dim3(8192 / 32, 1024 / 32), 256, 0, stream>>>(Wff1, wff1T, 1024, 8192);
  cvtT_kernel<<<dim3(1024 / 32, 4096 / 32), 256, 0, stream>>>(Wff2, wff2T, 4096, 1024);

  // LayerNorms
  ln_kernel<<<4096, 256, 0, stream>>>(x, g1, xn16, nullptr);
  ln_kernel<<<4096, 256, 0, stream>>>(y, g2, yn16, ynf);

  // q = (xn @ Wq) * 1/8    kv = yn @ Wkv
  gemm_ring<0, false><<<dim3(8, 32), 256, 0, stream>>>(
      xn16, wqT, 4096, 1024, 1024, q16, nullptr, nullptr, 0.125f);
  gemm_ring<0, false><<<dim3(1, 32), 256, 0, stream>>>(
      yn16, wkvT, 4096, 128, 1024, kv16, nullptr, nullptr, 1.0f);

  // attention
  attn_kernel<<<dim3(32, 16), 256, 0, stream>>>(q16, kv16, ao16);

  // out = attn @ Wo + yn   (f32, into d_out as scratch)
  gemm_ring<1, false><<<dim3(8, 32), 256, 0, stream>>>(
      ao16, woT, 4096, 1024, 1024, nullptr, outf, ynf, 1.0f);

  // ln_out = LN(out) * g_out  (f32)
  ln_kernel<<<4096, 256, 0, stream>>>(outf, g_out, nullptr, lnout);

  // act = silu(gate) * val   (fused dual-B GEMM over Wff1^T)
  gemm_ring<2, true><<<dim3(32, 32), 256, 0, stream>>>(
      yn16, wff1T, 4096, 4096, 1024, act16, nullptr, nullptr, 1.0f);

  // d_out = act @ Wff2 + ln_out
  gemm_ring<1, false><<<dim3(8, 32), 256, 0, stream>>>(
      act16, wff2T, 4096, 1024, 4096, nullptr, outf, lnout, 1.0f);
}